// Round 1
// baseline (8461.319 us; speedup 1.0000x reference)
//
#include <hip/hip_runtime.h>
#include <math.h>

typedef long long i64;

#define NB 4
#define NPAS 10
#define PLEN 400
#define QLEN 50
#define EDIM 256
#define CDIM 768
#define EMB 1024
#define HD 256
#define NHEADS 8
#define DH 32
#define DFF 1024
#define NTOKQ (NB*QLEN)        // 200
#define NTOKP (NB*NPAS*PLEN)   // 16000
#define NTOK  (NTOKQ+NTOKP)    // 16200
#define ATT_SCALE 0.17677669529663687f

// output offsets (floats)
#define OFF_BETA 0
#define OFF_PROB 40
#define OFF_MQ   44
#define OFF_QM   51244
#define OFF_MP   51444
#define OFF_PM   4147444

__device__ __forceinline__ float wsum(float v) {
#pragma unroll
  for (int o = 32; o > 0; o >>= 1) v += __shfl_xor(v, o);
  return v;
}
__device__ __forceinline__ float wmax(float v) {
#pragma unroll
  for (int o = 32; o > 0; o >>= 1) v = fmaxf(v, __shfl_xor(v, o));
  return v;
}

// ---------------- concat [e|c] -> X (NTOK x EMB) ----------------
__global__ void k_concat(const float* __restrict__ eq, const float* __restrict__ cq,
                         const float* __restrict__ ep, const float* __restrict__ cp,
                         float* __restrict__ X) {
  int idx = blockIdx.x * 256 + threadIdx.x;   // float4 index, grid exact
  int e = idx * 4;
  int row = e / EMB, c = e % EMB;
  float4 v;
  if (row < NTOKQ) {
    if (c < EDIM) v = *(const float4*)(eq + (i64)row * EDIM + c);
    else          v = *(const float4*)(cq + (i64)row * CDIM + (c - EDIM));
  } else {
    int t = row - NTOKQ;
    if (c < EDIM) v = *(const float4*)(ep + (i64)t * EDIM + c);
    else          v = *(const float4*)(cp + (i64)t * CDIM + (c - EDIM));
  }
  *(float4*)(X + (i64)row * EMB + c) = v;
}

// ---------------- generic matmul C = A(MxK) @ W(NxK)^T + b, opt GELU ----------------
template <int ACT>
__global__ __launch_bounds__(256) void k_mm(const float* __restrict__ A,
                                            const float* __restrict__ W,
                                            const float* __restrict__ bias,
                                            float* __restrict__ C,
                                            int M, int N, int K) {
  __shared__ float As[64][33];
  __shared__ float Ws[64][33];
  int tid = threadIdx.x;
  int tx = tid & 15, ty = tid >> 4;
  int rowBase = blockIdx.y * 64, colBase = blockIdx.x * 64;
  float acc[4][4] = {};
  int r0 = tid >> 3;
  int c = (tid & 7) << 2;
  for (int k0 = 0; k0 < K; k0 += 32) {
#pragma unroll
    for (int s = 0; s < 2; ++s) {
      int rr = r0 + s * 32;
      int gr = rowBase + rr;
      float4 av = {0.f, 0.f, 0.f, 0.f};
      if (gr < M) av = *(const float4*)(A + (i64)gr * K + k0 + c);
      As[rr][c] = av.x; As[rr][c + 1] = av.y; As[rr][c + 2] = av.z; As[rr][c + 3] = av.w;
      int gn = colBase + rr;
      float4 wv = {0.f, 0.f, 0.f, 0.f};
      if (gn < N) wv = *(const float4*)(W + (i64)gn * K + k0 + c);
      Ws[rr][c] = wv.x; Ws[rr][c + 1] = wv.y; Ws[rr][c + 2] = wv.z; Ws[rr][c + 3] = wv.w;
    }
    __syncthreads();
#pragma unroll
    for (int kk = 0; kk < 32; ++kk) {
      float a[4], w[4];
#pragma unroll
      for (int i = 0; i < 4; ++i) a[i] = As[ty * 4 + i][kk];
#pragma unroll
      for (int j = 0; j < 4; ++j) w[j] = Ws[tx * 4 + j][kk];
#pragma unroll
      for (int i = 0; i < 4; ++i)
#pragma unroll
        for (int j = 0; j < 4; ++j) acc[i][j] += a[i] * w[j];
    }
    __syncthreads();
  }
#pragma unroll
  for (int i = 0; i < 4; ++i) {
    int row = rowBase + ty * 4 + i;
    if (row >= M) continue;
#pragma unroll
    for (int j = 0; j < 4; ++j) {
      int col = colBase + tx * 4 + j;
      if (col >= N) continue;
      float v = acc[i][j] + bias[col];
      if (ACT == 2) v = 0.5f * v * (1.f + erff(v * 0.70710678118f));
      C[(i64)row * N + col] = v;
    }
  }
}

// ---------------- fused highway layer: out = g*relu(xWt+bt) + (1-g)*x ----------------
__global__ __launch_bounds__(256) void k_highway(const float* __restrict__ A,
                                                 const float* __restrict__ Wt,
                                                 const float* __restrict__ bt,
                                                 const float* __restrict__ Wg,
                                                 const float* __restrict__ bg,
                                                 float* __restrict__ C, int M) {
  __shared__ float As[64][33];
  __shared__ float Ts[64][33];
  __shared__ float Gs[64][33];
  int tid = threadIdx.x;
  int tx = tid & 15, ty = tid >> 4;
  int rowBase = blockIdx.y * 64, colBase = blockIdx.x * 64;
  float at[4][4] = {};
  float ag[4][4] = {};
  int r0 = tid >> 3;
  int c = (tid & 7) << 2;
  for (int k0 = 0; k0 < EMB; k0 += 32) {
#pragma unroll
    for (int s = 0; s < 2; ++s) {
      int rr = r0 + s * 32;
      int gr = rowBase + rr;
      float4 av = {0.f, 0.f, 0.f, 0.f};
      if (gr < M) av = *(const float4*)(A + (i64)gr * EMB + k0 + c);
      As[rr][c] = av.x; As[rr][c + 1] = av.y; As[rr][c + 2] = av.z; As[rr][c + 3] = av.w;
      int gn = colBase + rr;  // N = EMB, grid exact
      float4 tv = *(const float4*)(Wt + (i64)gn * EMB + k0 + c);
      Ts[rr][c] = tv.x; Ts[rr][c + 1] = tv.y; Ts[rr][c + 2] = tv.z; Ts[rr][c + 3] = tv.w;
      float4 gv = *(const float4*)(Wg + (i64)gn * EMB + k0 + c);
      Gs[rr][c] = gv.x; Gs[rr][c + 1] = gv.y; Gs[rr][c + 2] = gv.z; Gs[rr][c + 3] = gv.w;
    }
    __syncthreads();
#pragma unroll
    for (int kk = 0; kk < 32; ++kk) {
      float a[4], t[4], g[4];
#pragma unroll
      for (int i = 0; i < 4; ++i) a[i] = As[ty * 4 + i][kk];
#pragma unroll
      for (int j = 0; j < 4; ++j) { t[j] = Ts[tx * 4 + j][kk]; g[j] = Gs[tx * 4 + j][kk]; }
#pragma unroll
      for (int i = 0; i < 4; ++i)
#pragma unroll
        for (int j = 0; j < 4; ++j) { at[i][j] += a[i] * t[j]; ag[i][j] += a[i] * g[j]; }
    }
    __syncthreads();
  }
#pragma unroll
  for (int i = 0; i < 4; ++i) {
    int row = rowBase + ty * 4 + i;
    if (row >= M) continue;
#pragma unroll
    for (int j = 0; j < 4; ++j) {
      int col = colBase + tx * 4 + j;
      float t = fmaxf(at[i][j] + bt[col], 0.f);
      float g = 1.f / (1.f + __expf(-(ag[i][j] + bg[col])));
      float x = A[(i64)row * EMB + col];
      C[(i64)row * EMB + col] = g * t + (1.f - g) * x;
    }
  }
}

// ---------------- residual + layernorm, in place: X = LN(X + Hh) ----------------
__global__ void k_lnres(float* __restrict__ X, const float* __restrict__ Hh,
                        const float* __restrict__ g, const float* __restrict__ b) {
  int row = blockIdx.x;
  int lane = threadIdx.x;
  float4 xv = *(float4*)(X + (i64)row * HD + lane * 4);
  float4 hv = *(const float4*)(Hh + (i64)row * HD + lane * 4);
  float v0 = xv.x + hv.x, v1 = xv.y + hv.y, v2 = xv.z + hv.z, v3 = xv.w + hv.w;
  float m = wsum(v0 + v1 + v2 + v3) * (1.f / HD);
  float d0 = v0 - m, d1 = v1 - m, d2 = v2 - m, d3 = v3 - m;
  float var = wsum(d0 * d0 + d1 * d1 + d2 * d2 + d3 * d3) * (1.f / HD);
  float rstd = rsqrtf(var + 1e-5f);
  float4 gv = *(const float4*)(g + lane * 4);
  float4 bv = *(const float4*)(b + lane * 4);
  float4 o;
  o.x = d0 * rstd * gv.x + bv.x;
  o.y = d1 * rstd * gv.y + bv.y;
  o.z = d2 * rstd * gv.z + bv.z;
  o.w = d3 * rstd * gv.w + bv.w;
  *(float4*)(X + (i64)row * HD + lane * 4) = o;
}

// ---------------- MHA core: per (seq, head) block; online softmax ----------------
__global__ __launch_bounds__(256) void k_attn(const float* __restrict__ qkv,
                                              float* __restrict__ O,
                                              const int* __restrict__ lens,
                                              int S, int tokBase) {
  __shared__ float Ks[PLEN * DH];  // 51.2 KB
  int seq = blockIdx.x >> 3, head = blockIdx.x & 7;
  int len = lens[seq];
  int base = tokBase + seq * S;
  int hoff = head * DH;
  for (int idx = threadIdx.x; idx < S * DH; idx += 256) {
    int t = idx >> 5, d = idx & 31;
    Ks[idx] = qkv[(i64)(base + t) * 768 + 256 + hoff + d];
  }
  __syncthreads();
  for (int r = threadIdx.x; r < S; r += 256) {
    float q[DH];
#pragma unroll
    for (int d = 0; d < DH; ++d) q[d] = qkv[(i64)(base + r) * 768 + hoff + d];
    float mx = -1e30f, l = 0.f;
    float acc[DH] = {};
    for (int j = 0; j < S; ++j) {
      float s;
      if (j >= len) s = -1e9f;
      else {
        s = 0.f;
#pragma unroll
        for (int d = 0; d < DH; ++d) s += q[d] * Ks[j * DH + d];
        s *= ATT_SCALE;
      }
      float mn = fmaxf(mx, s);
      float corr = __expf(mx - mn);
      float e = __expf(s - mn);
      l = l * corr + e;
      const float* vrow = qkv + (i64)(base + j) * 768 + 512 + hoff;
#pragma unroll
      for (int d = 0; d < DH; ++d) acc[d] = acc[d] * corr + e * vrow[d];
      mx = mn;
    }
    float inv = 1.f / l;
#pragma unroll
    for (int d = 0; d < DH; ++d) O[(i64)(base + r) * HD + hoff + d] = acc[d] * inv;
  }
}

// ---------------- row dot with weight vector (len HD) ----------------
__global__ void k_rowdot(const float* __restrict__ X, const float* __restrict__ w,
                         float* __restrict__ out) {
  int row = blockIdx.x;
  int lane = threadIdx.x;
  float4 x = *(const float4*)(X + (i64)row * HD + lane * 4);
  float4 wv = *(const float4*)(w + lane * 4);
  float s = wsum(x.x * wv.x + x.y * wv.y + x.z * wv.z + x.w * wv.w);
  if (lane == 0) out[row] = s;
}

// ---------------- U[bk,p,q] = epwp + eqwq + dot(Ep, Eq*wx) ----------------
__global__ __launch_bounds__(256) void k_u(const float* __restrict__ E,
                                           const float* __restrict__ dual,
                                           const float* __restrict__ epwp,
                                           const float* __restrict__ eqwq,
                                           float* __restrict__ U) {
  __shared__ float Eqx[QLEN][HD + 1];
  int bk = blockIdx.x, b = bk / NPAS;
  for (int idx = threadIdx.x; idx < QLEN * HD; idx += 256) {
    int q = idx >> 8, h = idx & 255;
    Eqx[q][h] = E[(i64)(b * QLEN + q) * HD + h] * dual[2 * HD + h];
  }
  __syncthreads();
  int wave = threadIdx.x >> 6, lane = threadIdx.x & 63;
  for (int p = wave; p < PLEN; p += 4) {
    const float* ep = E + (i64)(NTOKQ + bk * PLEN + p) * HD;
    if (lane < QLEN) {
      float s = 0.f;
#pragma unroll 8
      for (int h = 0; h < HD; ++h) s += ep[h] * Eqx[lane][h];
      U[(i64)(bk * PLEN + p) * QLEN + lane] = epwp[bk * PLEN + p] + eqwq[b * QLEN + lane] + s;
    }
  }
}

// ---------------- Bsm: softmax over p (column), U (bk,400,50) -> Bsm ----------------
__global__ void k_softmax_col(const float* __restrict__ U, float* __restrict__ Bsm) {
  int col = blockIdx.x * 4 + (threadIdx.x >> 6);  // 2000 columns
  int lane = threadIdx.x & 63;
  int bk = col / QLEN, q = col % QLEN;
  const float* Ucol = U + (i64)bk * PLEN * QLEN + q;
  float v[7];
#pragma unroll
  for (int i = 0; i < 7; ++i) {
    int p = lane + i * 64;
    v[i] = (p < PLEN) ? Ucol[(i64)p * QLEN] : -1e30f;
  }
  float m = v[0];
#pragma unroll
  for (int i = 1; i < 7; ++i) m = fmaxf(m, v[i]);
  m = wmax(m);
  float s = 0.f;
#pragma unroll
  for (int i = 0; i < 7; ++i) {
    int p = lane + i * 64;
    v[i] = (p < PLEN) ? __expf(v[i] - m) : 0.f;
    s += v[i];
  }
  s = wsum(s);
  float inv = 1.f / s;
#pragma unroll
  for (int i = 0; i < 7; ++i) {
    int p = lane + i * 64;
    if (p < PLEN) Bsm[(i64)bk * PLEN * QLEN + (i64)p * QLEN + q] = v[i] * inv;
  }
}

// ---------------- Asm: row softmax in place (16000 rows of 50) ----------------
__global__ void k_softmax_row(float* __restrict__ U) {
  int row = blockIdx.x * 4 + (threadIdx.x >> 6);
  int lane = threadIdx.x & 63;
  float v = (lane < QLEN) ? U[(i64)row * QLEN + lane] : -1e30f;
  float m = wmax(v);
  float e = (lane < QLEN) ? __expf(v - m) : 0.f;
  float s = wsum(e);
  if (lane < QLEN) U[(i64)row * QLEN + lane] = e / s;
}

// ---------------- A-type: out[(bk*400+p)*HD+h] = sum_q in[q*HD+h]*Asm[p,q] ----------------
__global__ __launch_bounds__(256) void k_aX(const float* __restrict__ inQ, int strideSel,
                                            const float* __restrict__ Asm,
                                            float* __restrict__ out) {
  int bk = blockIdx.x, b = bk / NPAS;
  const float* in = inQ + (i64)(strideSel ? bk : b) * QLEN * HD;
  __shared__ float AsmL[200][52];
  int tid = threadIdx.x;
  float inr[QLEN];
#pragma unroll
  for (int q = 0; q < QLEN; ++q) inr[q] = in[(i64)q * HD + tid];
  for (int half = 0; half < 2; ++half) {
    __syncthreads();
    for (int idx = tid; idx < 200 * QLEN; idx += 256)
      AsmL[idx / QLEN][idx % QLEN] = Asm[(i64)(bk * PLEN + half * 200) * QLEN + idx];
    __syncthreads();
    for (int p = 0; p < 200; ++p) {
      float acc = 0.f;
#pragma unroll
      for (int q = 0; q < QLEN; ++q) acc += inr[q] * AsmL[p][q];
      out[(i64)(bk * PLEN + half * 200 + p) * HD + tid] = acc;
    }
  }
}

// ---------------- B-type: out[(bk*50+q)*HD+h] = sum_p in[p*HD+h]*Bsm[p,q] ----------------
__global__ __launch_bounds__(256) void k_bX(const float* __restrict__ inP,
                                            const float* __restrict__ Bsm,
                                            float* __restrict__ out) {
  int bk = blockIdx.x;
  const float* in = inP + (i64)bk * PLEN * HD;
  __shared__ float BsmL[200][52];
  int tid = threadIdx.x;
  float acc[QLEN] = {};
  for (int half = 0; half < 2; ++half) {
    __syncthreads();
    for (int idx = tid; idx < 200 * QLEN; idx += 256)
      BsmL[idx / QLEN][idx % QLEN] = Bsm[(i64)(bk * PLEN + half * 200) * QLEN + idx];
    __syncthreads();
    for (int p = 0; p < 200; ++p) {
      float e = in[(i64)(half * 200 + p) * HD + tid];
#pragma unroll
      for (int q = 0; q < QLEN; ++q) acc[q] += e * BsmL[p][q];
    }
  }
#pragma unroll
  for (int q = 0; q < QLEN; ++q) out[(i64)(bk * QLEN + q) * HD + tid] = acc[q];
}

// ---------------- max over k: (B,NP,QLEN,HD) -> (B,QLEN,HD) ----------------
__global__ void k_maxk(const float* __restrict__ Bs, float* __restrict__ Bm) {
  int idx = blockIdx.x * 256 + threadIdx.x;
  if (idx >= NB * QLEN * HD) return;
  int b = idx / (QLEN * HD), r = idx % (QLEN * HD);
  float m = -1e30f;
#pragma unroll
  for (int k = 0; k < NPAS; ++k) m = fmaxf(m, Bs[(i64)(b * NPAS + k) * QLEN * HD + r]);
  Bm[idx] = m;
}

// ---------------- fused G-build + mod projection (8 tokens per block) ----------------
__global__ __launch_bounds__(256) void k_src(const float* __restrict__ epBase,
                                             const float* __restrict__ x1,
                                             const float* __restrict__ x2,
                                             const float* __restrict__ Wm,
                                             const float* __restrict__ bm,
                                             float* __restrict__ out, int ntok) {
  int t0 = blockIdx.x * 8;
  int tid = threadIdx.x;
  __shared__ float g[8][5 * HD];  // 40 KB
#pragma unroll
  for (int t = 0; t < 8; ++t) {
    int tok = t0 + t;
    float ep = 0.f, a1 = 0.f, a2 = 0.f;
    if (tok < ntok) {
      ep = epBase[(i64)tok * HD + tid];
      a1 = x1[(i64)tok * HD + tid];
      a2 = x2[(i64)tok * HD + tid];
    }
    g[t][tid] = ep;
    g[t][HD + tid] = a1;
    g[t][2 * HD + tid] = a2;
    g[t][3 * HD + tid] = ep * a1;
    g[t][4 * HD + tid] = ep * a2;
  }
  __syncthreads();
  float acc[8] = {};
  const float4* wrow = (const float4*)(Wm + (i64)tid * 5 * HD);
  for (int j4 = 0; j4 < 5 * HD / 4; ++j4) {
    float4 w = wrow[j4];
    int j = j4 * 4;
#pragma unroll
    for (int t = 0; t < 8; ++t)
      acc[t] += g[t][j] * w.x + g[t][j + 1] * w.y + g[t][j + 2] * w.z + g[t][j + 3] * w.w;
  }
  float bias = bm[tid];
#pragma unroll
  for (int t = 0; t < 8; ++t) {
    int tok = t0 + t;
    if (tok < ntok) out[(i64)tok * HD + tid] = acc[t] + bias;
  }
}

// ---------------- outputs ----------------
__global__ void k_beta(const float* __restrict__ Mp, const float* __restrict__ rw,
                       float* __restrict__ outv) {
  int bk = blockIdx.x;
  int lane = threadIdx.x;
  const float* m1 = Mp + (i64)bk * PLEN * HD;  // p = 0
  float4 x = *(const float4*)(m1 + lane * 4);
  float4 w = *(const float4*)(rw + lane * 4);
  float s = wsum(x.x * w.x + x.y * w.y + x.z * w.z + x.w * w.w);
  if (lane == 0) outv[bk] = 1.f / (1.f + __expf(-s));
}

__global__ void k_prob(const float* __restrict__ Mp, const float* __restrict__ aw,
                       float* __restrict__ outv) {
  int b = blockIdx.x;
  int lane = threadIdx.x;
  float s = 0.f;
#pragma unroll
  for (int k = 0; k < NPAS; ++k) {
    const float* m1 = Mp + (i64)(b * NPAS + k) * PLEN * HD;
    float4 x = *(const float4*)(m1 + lane * 4);
    float4 w = *(const float4*)(aw + (i64)k * HD + lane * 4);
    s += x.x * w.x + x.y * w.y + x.z * w.z + x.w * w.w;
  }
  s = wsum(s);
  if (lane == 0) outv[b] = 1.f / (1.f + __expf(-s));
}

__global__ void k_masks(const int* __restrict__ qlen, const int* __restrict__ slen,
                        float* __restrict__ out) {
  int idx = blockIdx.x * 256 + threadIdx.x;
  if (idx < NTOKQ) {
    int b = idx / QLEN, i = idx % QLEN;
    out[OFF_QM + idx] = (i >= qlen[b]) ? 1.f : 0.f;
  }
  if (idx < NTOKP) {
    int s = idx / PLEN, i = idx % PLEN;
    out[OFF_PM + idx] = (i >= slen[s]) ? 1.f : 0.f;
  }
}

__global__ void k_copy4(const float* __restrict__ src, float* __restrict__ dst, int n4) {
  int idx = blockIdx.x * 256 + threadIdx.x;
  if (idx < n4) ((float4*)dst)[idx] = ((const float4*)src)[idx];
}

// =======================================================================
extern "C" void kernel_launch(void* const* d_in, const int* in_sizes, int n_in,
                              void* d_out, int out_size, void* d_ws, size_t ws_size,
                              hipStream_t stream) {
  const float* e_q = (const float*)d_in[0];
  const float* c_q = (const float*)d_in[1];
  const float* e_p = (const float*)d_in[2];
  const float* c_p = (const float*)d_in[3];
  const int* qlen = (const int*)d_in[4];
  const int* slen = (const int*)d_in[5];
  const float* hwt1w = (const float*)d_in[6];
  const float* hwt1b = (const float*)d_in[7];
  const float* hwg1w = (const float*)d_in[8];
  const float* hwg1b = (const float*)d_in[9];
  const float* hwt2w = (const float*)d_in[10];
  const float* hwt2b = (const float*)d_in[11];
  const float* hwg2w = (const float*)d_in[12];
  const float* hwg2b = (const float*)d_in[13];
  const float* slw = (const float*)d_in[14];
  const float* slb = (const float*)d_in[15];
  const float* encsW[12];
  const float* encqW[12];
  const float* encpW[12];
  for (int i = 0; i < 12; ++i) {
    encsW[i] = (const float*)d_in[16 + i];
    encqW[i] = (const float*)d_in[28 + i];
    encpW[i] = (const float*)d_in[40 + i];
  }
  const float* dualw = (const float*)d_in[52];
  const float* modqw = (const float*)d_in[53];
  const float* modqb = (const float*)d_in[54];
  const float* modpw = (const float*)d_in[55];
  const float* modpb = (const float*)d_in[56];
  const float* rankw = (const float*)d_in[57];
  const float* answ = (const float*)d_in[58];
  float* out = (float*)d_out;

  // workspace layout (floats)
  float* ws = (float*)d_ws;
  float* W1 = ws;                    // 16,588,800 (X0 / h2 / enc tmp1)
  float* W2 = ws + 16588800;         // 16,588,800 (h1 / ff buf / A1s,A2s)
  float* W3 = ws + 33177600;         // 12,441,600 (qkv / Asm,Bsm)
  float* Ebuf = ws + 45619200;       // 4,147,200  (encs state: Eq|Ep; later attn tmp)
  float* Obuf = ws + 49766400;       // 4,147,200  (attn out; later srcp/encp state = M_p)
  float* MQb = ws + 53913600;        // 51,200     (srcq/encq state = M_q)
  float* EPWP = ws + 53964800;       // 16,000
  float* EQWQ = ws + 53980800;       // 200
  float* B1s = ws + 53981000;        // 512,000
  float* B2s = ws + 54493000;        // 512,000
  float* B1m = ws + 55005000;        // 51,200
  float* B2m = ws + 55056200;        // 51,200   (end: 55,107,400 floats = 220.4 MB)
  float* A1s = W2;
  float* A2s = W2 + 4096000;
  float* ASMb = W3;
  float* BSMb = W3 + 800000;

  auto mm = [&](const float* A, const float* Wt, const float* bias, float* C,
                int M, int N, int K, int act) {
    dim3 g(N / 64, (M + 63) / 64);
    if (act == 2)
      k_mm<2><<<g, 256, 0, stream>>>(A, Wt, bias, C, M, N, K);
    else
      k_mm<0><<<g, 256, 0, stream>>>(A, Wt, bias, C, M, N, K);
  };

  struct AttnSpec { int nseq, S, base; const int* lens; };
  auto enc = [&](float* state, int M, const float* const* w, const AttnSpec* specs,
                 int nspec, float* qkvB, float* attnB, float* t1, float* ffB) {
    for (int l = 0; l < 2; ++l) {
      const float* aw = w[0] + (i64)l * 3 * HD * HD;
      const float* ab = w[1] + l * 3 * HD;
      const float* owt = w[2] + (i64)l * HD * HD;
      const float* ob = w[3] + l * HD;
      const float* g1 = w[4] + l * HD;
      const float* b1 = w[5] + l * HD;
      const float* f1w = w[6] + (i64)l * DFF * HD;
      const float* f1b = w[7] + l * DFF;
      const float* f2w = w[8] + (i64)l * HD * DFF;
      const float* f2b = w[9] + l * HD;
      const float* g2 = w[10] + l * HD;
      const float* b2 = w[11] + l * HD;
      mm(state, aw, ab, qkvB, M, 3 * HD, HD, 0);
      for (int s = 0; s < nspec; ++s)
        k_attn<<<dim3(specs[s].nseq * NHEADS), dim3(256), 0, stream>>>(
            qkvB, attnB, specs[s].lens, specs[s].S, specs[s].base);
      mm(attnB, owt, ob, t1, M, HD, HD, 0);
      k_lnres<<<dim3(M), dim3(64), 0, stream>>>(state, t1, g1, b1);
      mm(state, f1w, f1b, ffB, M, DFF, HD, 2);
      mm(ffB, f2w, f2b, t1, M, HD, DFF, 0);
      k_lnres<<<dim3(M), dim3(64), 0, stream>>>(state, t1, g2, b2);
    }
  };

  // 1. concat
  k_concat<<<dim3(NTOK * EMB / 4 / 256), dim3(256), 0, stream>>>(e_q, c_q, e_p, c_p, W1);

  // 2. highway (two fused layers)
  dim3 hwg(EMB / 64, (NTOK + 63) / 64);
  k_highway<<<hwg, 256, 0, stream>>>(W1, hwt1w, hwt1b, hwg1w, hwg1b, W2, NTOK);
  k_highway<<<hwg, 256, 0, stream>>>(W2, hwt2w, hwt2b, hwg2w, hwg2b, W1, NTOK);

  // 3. shared linear -> E (16200 x 256)
  mm(W1, slw, slb, Ebuf, NTOK, HD, EMB, 0);

  // 4. shared encoder (q seqs + p seqs)
  AttnSpec specs[2] = {{NB, QLEN, 0, qlen}, {NB * NPAS, PLEN, NTOKQ, slen}};
  enc(Ebuf, NTOK, encsW, specs, 2, W3, Obuf, W1, W2);

  // 5. dual attention
  k_rowdot<<<dim3(NTOKP), dim3(64), 0, stream>>>(Ebuf + (i64)NTOKQ * HD, dualw, EPWP);
  k_rowdot<<<dim3(NTOKQ), dim3(64), 0, stream>>>(Ebuf, dualw + HD, EQWQ);
  k_u<<<dim3(NB * NPAS), dim3(256), 0, stream>>>(Ebuf, dualw, EPWP, EQWQ, ASMb);
  k_softmax_col<<<dim3(500), dim3(256), 0, stream>>>(ASMb, BSMb);
  k_softmax_row<<<dim3(4000), dim3(256), 0, stream>>>(ASMb);
  k_aX<<<dim3(NB * NPAS), dim3(256), 0, stream>>>(Ebuf, 0, ASMb, A1s);
  k_bX<<<dim3(NB * NPAS), dim3(256), 0, stream>>>(Ebuf + (i64)NTOKQ * HD, BSMb, B1s);
  k_aX<<<dim3(NB * NPAS), dim3(256), 0, stream>>>(B1s, 1, ASMb, A2s);
  k_bX<<<dim3(NB * NPAS), dim3(256), 0, stream>>>(A1s, BSMb, B2s);
  k_maxk<<<dim3(200), dim3(256), 0, stream>>>(B1s, B1m);
  k_maxk<<<dim3(200), dim3(256), 0, stream>>>(B2s, B2m);

  // 6. fused G + mod projections
  k_src<<<dim3(2000), dim3(256), 0, stream>>>(Ebuf + (i64)NTOKQ * HD, A1s, A2s, modpw,
                                              modpb, Obuf, NTOKP);
  k_src<<<dim3(25), dim3(256), 0, stream>>>(Ebuf, B1m, B2m, modqw, modqb, MQb, NTOKQ);

  // 7. model encoders (E buffer is dead now; reuse as attn tmp)
  AttnSpec sp2 = {NB * NPAS, PLEN, 0, slen};
  enc(Obuf, NTOKP, encpW, &sp2, 1, W3, Ebuf, W1, W2);
  AttnSpec sq2 = {NB, QLEN, 0, qlen};
  enc(MQb, NTOKQ, encqW, &sq2, 1, W3, Ebuf, W1, W2);

  // 8. outputs
  k_beta<<<dim3(NB * NPAS), dim3(64), 0, stream>>>(Obuf, rankw, out + OFF_BETA);
  k_prob<<<dim3(NB), dim3(64), 0, stream>>>(Obuf, answ, out + OFF_PROB);
  k_copy4<<<dim3(50), dim3(256), 0, stream>>>(MQb, out + OFF_MQ, NTOKQ * HD / 4);
  k_copy4<<<dim3(4000), dim3(256), 0, stream>>>(Obuf, out + OFF_MP, NTOKP * HD / 4);
  k_masks<<<dim3(63), dim3(256), 0, stream>>>(qlen, slen, out);
}

// Round 2
// 3992.569 us; speedup vs baseline: 2.1193x; 2.1193x over previous
//
#include <hip/hip_runtime.h>
#include <math.h>

typedef long long i64;
typedef __attribute__((ext_vector_type(8))) short short8;
typedef __attribute__((ext_vector_type(4))) float f32x4;

#define NB 4
#define NPAS 10
#define PLEN 400
#define QLEN 50
#define EDIM 256
#define CDIM 768
#define EMB 1024
#define HD 256
#define NHEADS 8
#define DH 32
#define DFF 1024
#define NTOKQ (NB*QLEN)        // 200
#define NTOKP (NB*NPAS*PLEN)   // 16000
#define NTOK  (NTOKQ+NTOKP)    // 16200
#define ATT_SCALE 0.17677669529663687f

// output offsets (floats)
#define OFF_BETA 0
#define OFF_PROB 40
#define OFF_MQ   44
#define OFF_QM   51244
#define OFF_MP   51444
#define OFF_PM   4147444

__device__ __forceinline__ float wsum(float v) {
#pragma unroll
  for (int o = 32; o > 0; o >>= 1) v += __shfl_xor(v, o);
  return v;
}
__device__ __forceinline__ float wmax(float v) {
#pragma unroll
  for (int o = 32; o > 0; o >>= 1) v = fmaxf(v, __shfl_xor(v, o));
  return v;
}
__device__ __forceinline__ float b2f(ushort u) { return __uint_as_float(((unsigned)u) << 16); }
__device__ __forceinline__ ushort f2b(float f) {
  unsigned u = __float_as_uint(f);
  return (ushort)((u + 0x7fffu + ((u >> 16) & 1u)) >> 16);
}
__device__ __forceinline__ void st_bf4(ushort* p, float a, float b, float c, float d) {
  ushort4 o = {f2b(a), f2b(b), f2b(c), f2b(d)};
  *(ushort4*)p = o;
}

// ---------------- weight fp32->bf16 conversion (19 arrays, one kernel) ----------------
struct CvtArgs { const float* src[19]; int len[19]; };
__global__ void k_cvt(CvtArgs a, ushort* __restrict__ dst) {
  i64 pos = ((i64)blockIdx.x * 256 + threadIdx.x) * 4;
  i64 off = 0; int s = 0;
#pragma unroll 1
  for (; s < 19; ++s) { if (pos < off + a.len[s]) break; off += a.len[s]; }
  if (s >= 19) return;
  float4 v = *(const float4*)(a.src[s] + (pos - off));
  st_bf4(dst + pos, v.x, v.y, v.z, v.w);
}

// ---------------- concat [e|c] -> X bf16 (NTOK x EMB) ----------------
__global__ void k_concat(const float* __restrict__ eq, const float* __restrict__ cq,
                         const float* __restrict__ ep, const float* __restrict__ cp,
                         ushort* __restrict__ X) {
  int idx = blockIdx.x * 256 + threadIdx.x;   // 4-elem index, grid exact
  i64 e = (i64)idx * 4;
  int row = (int)(e / EMB), c = (int)(e % EMB);
  float4 v;
  if (row < NTOKQ) {
    if (c < EDIM) v = *(const float4*)(eq + (i64)row * EDIM + c);
    else          v = *(const float4*)(cq + (i64)row * CDIM + (c - EDIM));
  } else {
    int t = row - NTOKQ;
    if (c < EDIM) v = *(const float4*)(ep + (i64)t * EDIM + c);
    else          v = *(const float4*)(cp + (i64)t * CDIM + (c - EDIM));
  }
  st_bf4(X + (i64)row * EMB + c, v.x, v.y, v.z, v.w);
}

// ---------------- MFMA bf16 GEMM: C = A(MxK) @ W(NxK)^T + b ----------------
// ACT: 0 none, 1 relu, 2 gelu, 3 sigmoid. Dual-output fp32/bf16.
// BM=BN=128, BK=64, 4 waves (2x2), 4x4 16x16 frags per wave.
template <int ACT, bool WF32, bool WBF>
__global__ __launch_bounds__(256) void k_gemm(const ushort* __restrict__ A,
                                              const ushort* __restrict__ W,
                                              const float* __restrict__ bias,
                                              float* __restrict__ Cf,
                                              ushort* __restrict__ Cb,
                                              int M, int N, int K) {
  __shared__ ushort Al[128 * 64];
  __shared__ ushort Bl[128 * 64];
  const int tid = threadIdx.x;
  const int lane = tid & 63;
  const int wave = tid >> 6;
  const int wm = wave >> 1, wn = wave & 1;
  const int r0 = blockIdx.y * 128, c0 = blockIdx.x * 128;
  const int srow = tid >> 3;      // 0..31 (+ch*32)
  const int scol = tid & 7;       // 16B slot within 128B row
  f32x4 acc[4][4] = {};
  short8 Asr[4], Bsr[4];
#pragma unroll
  for (int ch = 0; ch < 4; ++ch) {
    int row = ch * 32 + srow;
    Asr[ch] = *(const short8*)(A + (i64)(r0 + row) * K + scol * 8);
    Bsr[ch] = *(const short8*)(W + (i64)(c0 + row) * K + scol * 8);
  }
  const int nk = K >> 6;
  for (int kt = 0; kt < nk; ++kt) {
#pragma unroll
    for (int ch = 0; ch < 4; ++ch) {
      int row = ch * 32 + srow;
      int slot = scol ^ (row & 7);
      *(short8*)(Al + row * 64 + slot * 8) = Asr[ch];
      *(short8*)(Bl + row * 64 + slot * 8) = Bsr[ch];
    }
    __syncthreads();
    if (kt + 1 < nk) {
      int k0 = (kt + 1) << 6;
#pragma unroll
      for (int ch = 0; ch < 4; ++ch) {
        int row = ch * 32 + srow;
        Asr[ch] = *(const short8*)(A + (i64)(r0 + row) * K + k0 + scol * 8);
        Bsr[ch] = *(const short8*)(W + (i64)(c0 + row) * K + k0 + scol * 8);
      }
    }
#pragma unroll
    for (int ks = 0; ks < 2; ++ks) {
      short8 af[4], bf[4];
      int c16 = ks * 4 + (lane >> 4);
#pragma unroll
      for (int m = 0; m < 4; ++m) {
        int arow = wm * 64 + m * 16 + (lane & 15);
        af[m] = *(const short8*)(Al + arow * 64 + ((c16 ^ (arow & 7)) * 8));
        int brow = wn * 64 + m * 16 + (lane & 15);
        bf[m] = *(const short8*)(Bl + brow * 64 + ((c16 ^ (brow & 7)) * 8));
      }
#pragma unroll
      for (int m = 0; m < 4; ++m)
#pragma unroll
        for (int n = 0; n < 4; ++n)
          acc[m][n] = __builtin_amdgcn_mfma_f32_16x16x32_bf16(af[m], bf[n], acc[m][n], 0, 0, 0);
    }
    __syncthreads();
  }
#pragma unroll
  for (int m = 0; m < 4; ++m) {
    int row = r0 + wm * 64 + m * 16 + (lane >> 4) * 4;
#pragma unroll
    for (int n = 0; n < 4; ++n) {
      int col = c0 + wn * 64 + n * 16 + (lane & 15);
      float bv = bias[col];
#pragma unroll
      for (int j = 0; j < 4; ++j) {
        if (row + j >= M) continue;
        float v = acc[m][n][j] + bv;
        if (ACT == 1) v = fmaxf(v, 0.f);
        if (ACT == 2) v = 0.5f * v * (1.f + erff(v * 0.70710678118f));
        if (ACT == 3) v = 1.f / (1.f + __expf(-v));
        if (WF32) Cf[(i64)(row + j) * N + col] = v;
        if (WBF)  Cb[(i64)(row + j) * N + col] = f2b(v);
      }
    }
  }
}

// ---------------- highway combine: h = g*t + (1-g)*x (all bf16) ----------------
__global__ void k_hwcomb(const ushort* __restrict__ T, const ushort* __restrict__ G,
                         const ushort* __restrict__ X, ushort* __restrict__ H) {
  i64 o = ((i64)blockIdx.x * 256 + threadIdx.x) * 8;
  ushort tb[8], gb[8], xb[8], hb[8];
  *(uint4*)tb = *(const uint4*)(T + o);
  *(uint4*)gb = *(const uint4*)(G + o);
  *(uint4*)xb = *(const uint4*)(X + o);
#pragma unroll
  for (int i = 0; i < 8; ++i) {
    float t = b2f(tb[i]), g = b2f(gb[i]), x = b2f(xb[i]);
    hb[i] = f2b(g * t + (1.f - g) * x);
  }
  *(uint4*)(H + o) = *(uint4*)hb;
}

// ---------------- residual + layernorm, fp32 state + bf16 copy ----------------
__global__ void k_lnres(float* __restrict__ X, ushort* __restrict__ Xb,
                        const float* __restrict__ Hh,
                        const float* __restrict__ g, const float* __restrict__ b) {
  int row = blockIdx.x;
  int lane = threadIdx.x;
  float4 xv = *(float4*)(X + (i64)row * HD + lane * 4);
  float4 hv = *(const float4*)(Hh + (i64)row * HD + lane * 4);
  float v0 = xv.x + hv.x, v1 = xv.y + hv.y, v2 = xv.z + hv.z, v3 = xv.w + hv.w;
  float m = wsum(v0 + v1 + v2 + v3) * (1.f / HD);
  float d0 = v0 - m, d1 = v1 - m, d2 = v2 - m, d3 = v3 - m;
  float var = wsum(d0 * d0 + d1 * d1 + d2 * d2 + d3 * d3) * (1.f / HD);
  float rstd = rsqrtf(var + 1e-5f);
  float4 gv = *(const float4*)(g + lane * 4);
  float4 bv = *(const float4*)(b + lane * 4);
  float4 o;
  o.x = d0 * rstd * gv.x + bv.x;
  o.y = d1 * rstd * gv.y + bv.y;
  o.z = d2 * rstd * gv.z + bv.z;
  o.w = d3 * rstd * gv.w + bv.w;
  *(float4*)(X + (i64)row * HD + lane * 4) = o;
  st_bf4(Xb + (i64)row * HD + lane * 4, o.x, o.y, o.z, o.w);
}

// ---------------- MHA core: per (seq, head) block; bf16 qkv in, bf16 O out ----------------
__global__ __launch_bounds__(256) void k_attn(const ushort* __restrict__ qkv,
                                              ushort* __restrict__ O,
                                              const int* __restrict__ lens,
                                              int S, int tokBase) {
  __shared__ float Ks[PLEN * DH];  // 51.2 KB
  int seq = blockIdx.x >> 3, head = blockIdx.x & 7;
  int len = lens[seq];
  int base = tokBase + seq * S;
  int hoff = head * DH;
  for (int idx = threadIdx.x; idx < S * DH; idx += 256) {
    int t = idx >> 5, d = idx & 31;
    Ks[idx] = b2f(qkv[(i64)(base + t) * 768 + 256 + hoff + d]);
  }
  __syncthreads();
  for (int r = threadIdx.x; r < S; r += 256) {
    float q[DH];
#pragma unroll
    for (int d = 0; d < DH; ++d) q[d] = b2f(qkv[(i64)(base + r) * 768 + hoff + d]);
    float mx = -1e30f, l = 0.f;
    float acc[DH] = {};
    for (int j = 0; j < S; ++j) {
      float s;
      if (j >= len) s = -1e9f;
      else {
        s = 0.f;
#pragma unroll
        for (int d = 0; d < DH; ++d) s += q[d] * Ks[j * DH + d];
        s *= ATT_SCALE;
      }
      float mn = fmaxf(mx, s);
      float corr = __expf(mx - mn);
      float e = __expf(s - mn);
      l = l * corr + e;
      const ushort* vrow = qkv + (i64)(base + j) * 768 + 512 + hoff;
#pragma unroll
      for (int d = 0; d < DH; ++d) acc[d] = acc[d] * corr + e * b2f(vrow[d]);
      mx = mn;
    }
    float inv = 1.f / l;
#pragma unroll
    for (int d = 0; d < DH; ++d) O[(i64)(base + r) * HD + hoff + d] = f2b(acc[d] * inv);
  }
}

// ---------------- row dot with weight vector (len HD) ----------------
__global__ void k_rowdot(const float* __restrict__ X, const float* __restrict__ w,
                         float* __restrict__ out) {
  int row = blockIdx.x;
  int lane = threadIdx.x;
  float4 x = *(const float4*)(X + (i64)row * HD + lane * 4);
  float4 wv = *(const float4*)(w + lane * 4);
  float s = wsum(x.x * wv.x + x.y * wv.y + x.z * wv.z + x.w * wv.w);
  if (lane == 0) out[row] = s;
}

// ---------------- U[bk,p,q] = epwp + eqwq + dot(Ep, Eq*wx) ----------------
__global__ __launch_bounds__(256) void k_u(const float* __restrict__ E,
                                           const float* __restrict__ dual,
                                           const float* __restrict__ epwp,
                                           const float* __restrict__ eqwq,
                                           float* __restrict__ U) {
  __shared__ float Eqx[QLEN][HD + 1];
  int bk = blockIdx.x, b = bk / NPAS;
  for (int idx = threadIdx.x; idx < QLEN * HD; idx += 256) {
    int q = idx >> 8, h = idx & 255;
    Eqx[q][h] = E[(i64)(b * QLEN + q) * HD + h] * dual[2 * HD + h];
  }
  __syncthreads();
  int wave = threadIdx.x >> 6, lane = threadIdx.x & 63;
  for (int p = wave; p < PLEN; p += 4) {
    const float* ep = E + (i64)(NTOKQ + bk * PLEN + p) * HD;
    if (lane < QLEN) {
      float s = 0.f;
#pragma unroll 8
      for (int h = 0; h < HD; ++h) s += ep[h] * Eqx[lane][h];
      U[(i64)(bk * PLEN + p) * QLEN + lane] = epwp[bk * PLEN + p] + eqwq[b * QLEN + lane] + s;
    }
  }
}

// ---------------- Bsm: softmax over p (column) ----------------
__global__ void k_softmax_col(const float* __restrict__ U, float* __restrict__ Bsm) {
  int col = blockIdx.x * 4 + (threadIdx.x >> 6);  // 2000 columns
  int lane = threadIdx.x & 63;
  int bk = col / QLEN, q = col % QLEN;
  const float* Ucol = U + (i64)bk * PLEN * QLEN + q;
  float v[7];
#pragma unroll
  for (int i = 0; i < 7; ++i) {
    int p = lane + i * 64;
    v[i] = (p < PLEN) ? Ucol[(i64)p * QLEN] : -1e30f;
  }
  float m = v[0];
#pragma unroll
  for (int i = 1; i < 7; ++i) m = fmaxf(m, v[i]);
  m = wmax(m);
  float s = 0.f;
#pragma unroll
  for (int i = 0; i < 7; ++i) {
    int p = lane + i * 64;
    v[i] = (p < PLEN) ? __expf(v[i] - m) : 0.f;
    s += v[i];
  }
  s = wsum(s);
  float inv = 1.f / s;
#pragma unroll
  for (int i = 0; i < 7; ++i) {
    int p = lane + i * 64;
    if (p < PLEN) Bsm[(i64)bk * PLEN * QLEN + (i64)p * QLEN + q] = v[i] * inv;
  }
}

// ---------------- Asm: row softmax in place ----------------
__global__ void k_softmax_row(float* __restrict__ U) {
  int row = blockIdx.x * 4 + (threadIdx.x >> 6);
  int lane = threadIdx.x & 63;
  float v = (lane < QLEN) ? U[(i64)row * QLEN + lane] : -1e30f;
  float m = wmax(v);
  float e = (lane < QLEN) ? __expf(v - m) : 0.f;
  float s = wsum(e);
  if (lane < QLEN) U[(i64)row * QLEN + lane] = e / s;
}

// ---------------- A-type: out[(bk*400+p)*HD+h] = sum_q in[q*HD+h]*Asm[p,q] ----------------
__global__ __launch_bounds__(256) void k_aX(const float* __restrict__ inQ, int strideSel,
                                            const float* __restrict__ Asm,
                                            float* __restrict__ out) {
  int bk = blockIdx.x, b = bk / NPAS;
  const float* in = inQ + (i64)(strideSel ? bk : b) * QLEN * HD;
  __shared__ float AsmL[200][52];
  int tid = threadIdx.x;
  float inr[QLEN];
#pragma unroll
  for (int q = 0; q < QLEN; ++q) inr[q] = in[(i64)q * HD + tid];
  for (int half = 0; half < 2; ++half) {
    __syncthreads();
    for (int idx = tid; idx < 200 * QLEN; idx += 256)
      AsmL[idx / QLEN][idx % QLEN] = Asm[(i64)(bk * PLEN + half * 200) * QLEN + idx];
    __syncthreads();
    for (int p = 0; p < 200; ++p) {
      float acc = 0.f;
#pragma unroll
      for (int q = 0; q < QLEN; ++q) acc += inr[q] * AsmL[p][q];
      out[(i64)(bk * PLEN + half * 200 + p) * HD + tid] = acc;
    }
  }
}

// ---------------- B-type: out[(bk*50+q)*HD+h] = sum_p in[p*HD+h]*Bsm[p,q] ----------------
__global__ __launch_bounds__(256) void k_bX(const float* __restrict__ inP,
                                            const float* __restrict__ Bsm,
                                            float* __restrict__ out) {
  int bk = blockIdx.x;
  const float* in = inP + (i64)bk * PLEN * HD;
  __shared__ float BsmL[200][52];
  int tid = threadIdx.x;
  float acc[QLEN] = {};
  for (int half = 0; half < 2; ++half) {
    __syncthreads();
    for (int idx = tid; idx < 200 * QLEN; idx += 256)
      BsmL[idx / QLEN][idx % QLEN] = Bsm[(i64)(bk * PLEN + half * 200) * QLEN + idx];
    __syncthreads();
    for (int p = 0; p < 200; ++p) {
      float e = in[(i64)(half * 200 + p) * HD + tid];
#pragma unroll
      for (int q = 0; q < QLEN; ++q) acc[q] += e * BsmL[p][q];
    }
  }
#pragma unroll
  for (int q = 0; q < QLEN; ++q) out[(i64)(bk * QLEN + q) * HD + tid] = acc[q];
}

// ---------------- max over k ----------------
__global__ void k_maxk(const float* __restrict__ Bs, float* __restrict__ Bm) {
  int idx = blockIdx.x * 256 + threadIdx.x;
  if (idx >= NB * QLEN * HD) return;
  int b = idx / (QLEN * HD), r = idx % (QLEN * HD);
  float m = -1e30f;
#pragma unroll
  for (int k = 0; k < NPAS; ++k) m = fmaxf(m, Bs[(i64)(b * NPAS + k) * QLEN * HD + r]);
  Bm[idx] = m;
}

// ---------------- G build: [ep | x1 | x2 | ep*x1 | ep*x2] bf16, K=1280 ----------------
__global__ void k_gbuild(const float* __restrict__ E, const float* __restrict__ x1,
                         const float* __restrict__ x2, ushort* __restrict__ Gt, int ntok) {
  int tok = blockIdx.x * 4 + (threadIdx.x >> 6);
  int h4 = (threadIdx.x & 63) * 4;
  if (tok >= ntok) return;
  float4 ep = *(const float4*)(E + (i64)tok * HD + h4);
  float4 a1 = *(const float4*)(x1 + (i64)tok * HD + h4);
  float4 a2 = *(const float4*)(x2 + (i64)tok * HD + h4);
  ushort* g = Gt + (i64)tok * 1280;
  st_bf4(g + h4, ep.x, ep.y, ep.z, ep.w);
  st_bf4(g + 256 + h4, a1.x, a1.y, a1.z, a1.w);
  st_bf4(g + 512 + h4, a2.x, a2.y, a2.z, a2.w);
  st_bf4(g + 768 + h4, ep.x * a1.x, ep.y * a1.y, ep.z * a1.z, ep.w * a1.w);
  st_bf4(g + 1024 + h4, ep.x * a2.x, ep.y * a2.y, ep.z * a2.z, ep.w * a2.w);
}

// ---------------- outputs ----------------
__global__ void k_beta(const float* __restrict__ Mp, const float* __restrict__ rw,
                       float* __restrict__ outv) {
  int bk = blockIdx.x;
  int lane = threadIdx.x;
  const float* m1 = Mp + (i64)bk * PLEN * HD;
  float4 x = *(const float4*)(m1 + lane * 4);
  float4 w = *(const float4*)(rw + lane * 4);
  float s = wsum(x.x * w.x + x.y * w.y + x.z * w.z + x.w * w.w);
  if (lane == 0) outv[bk] = 1.f / (1.f + __expf(-s));
}

__global__ void k_prob(const float* __restrict__ Mp, const float* __restrict__ aw,
                       float* __restrict__ outv) {
  int b = blockIdx.x;
  int lane = threadIdx.x;
  float s = 0.f;
#pragma unroll
  for (int k = 0; k < NPAS; ++k) {
    const float* m1 = Mp + (i64)(b * NPAS + k) * PLEN * HD;
    float4 x = *(const float4*)(m1 + lane * 4);
    float4 w = *(const float4*)(aw + (i64)k * HD + lane * 4);
    s += x.x * w.x + x.y * w.y + x.z * w.z + x.w * w.w;
  }
  s = wsum(s);
  if (lane == 0) outv[b] = 1.f / (1.f + __expf(-s));
}

__global__ void k_masks(const int* __restrict__ qlen, const int* __restrict__ slen,
                        float* __restrict__ out) {
  int idx = blockIdx.x * 256 + threadIdx.x;
  if (idx < NTOKQ) {
    int b = idx / QLEN, i = idx % QLEN;
    out[OFF_QM + idx] = (i >= qlen[b]) ? 1.f : 0.f;
  }
  if (idx < NTOKP) {
    int s = idx / PLEN, i = idx % PLEN;
    out[OFF_PM + idx] = (i >= slen[s]) ? 1.f : 0.f;
  }
}

__global__ void k_copy4(const float* __restrict__ src, float* __restrict__ dst, int n4) {
  int idx = blockIdx.x * 256 + threadIdx.x;
  if (idx < n4) ((float4*)dst)[idx] = ((const float4*)src)[idx];
}

// =======================================================================
extern "C" void kernel_launch(void* const* d_in, const int* in_sizes, int n_in,
                              void* d_out, int out_size, void* d_ws, size_t ws_size,
                              hipStream_t stream) {
  const float* e_q = (const float*)d_in[0];
  const float* c_q = (const float*)d_in[1];
  const float* e_p = (const float*)d_in[2];
  const float* c_p = (const float*)d_in[3];
  const int* qlen = (const int*)d_in[4];
  const int* slen = (const int*)d_in[5];
  const float* hwt1w = (const float*)d_in[6];
  const float* hwt1b = (const float*)d_in[7];
  const float* hwg1w = (const float*)d_in[8];
  const float* hwg1b = (const float*)d_in[9];
  const float* hwt2w = (const float*)d_in[10];
  const float* hwt2b = (const float*)d_in[11];
  const float* hwg2w = (const float*)d_in[12];
  const float* hwg2b = (const float*)d_in[13];
  const float* slw = (const float*)d_in[14];
  const float* slb = (const float*)d_in[15];
  const float* encsW[12];
  const float* encqW[12];
  const float* encpW[12];
  for (int i = 0; i < 12; ++i) {
    encsW[i] = (const float*)d_in[16 + i];
    encqW[i] = (const float*)d_in[28 + i];
    encpW[i] = (const float*)d_in[40 + i];
  }
  const float* dualw = (const float*)d_in[52];
  const float* modqw = (const float*)d_in[53];
  const float* modqb = (const float*)d_in[54];
  const float* modpw = (const float*)d_in[55];
  const float* modpb = (const float*)d_in[56];
  const float* rankw = (const float*)d_in[57];
  const float* answ = (const float*)d_in[58];
  float* out = (float*)d_out;

  // -------- workspace layout (byte offsets, all 512-aligned) --------
  char* ws = (char*)d_ws;
  // ES region [0, 67,108,864): enc scratch / highway T,G / Gp,Gq (time-disjoint)
  ushort* qkvB  = (ushort*)(ws + 0);            // 16384x768 bf16 = 25,165,824
  ushort* attnO = (ushort*)(ws + 25165824);     // 16384x256 bf16 = 8,388,608 (ends 33,554,432)
  float*  t1    = (float*) (ws + 0);            // 16384x256 f32 = 16,777,216 (aliases qkv)
  ushort* ffB   = (ushort*)(ws + 16777216);     // 16384x1024 bf16 = 33,554,432 (ends 50,331,648)
  ushort* Tb    = (ushort*)(ws + 0);            // 16384x1024 bf16
  ushort* Gb    = (ushort*)(ws + 33554432);     // ends 67,108,864
  ushort* GpB   = (ushort*)(ws + 0);            // 16384x1280 bf16 = 41,943,040
  ushort* GqB   = (ushort*)(ws + 44040192);     // 256x1280 bf16 = 655,360
  // RA [67,108,864): Xbf then h2
  ushort* Xbf   = (ushort*)(ws + 67108864);     // 16384x1024 bf16
  ushort* H2bf  = Xbf;
  // RB [100,663,296): h1 then A1s/A2s
  ushort* Hbf   = (ushort*)(ws + 100663296);
  float*  A1s   = (float*) (ws + 100663296);    // 16,384,000
  float*  A2s   = (float*) (ws + 117047296);    // 16,384,000 (ends 133,431,296 < 134,217,728)
  // persistent states
  float*  S_f32 = (float*) (ws + 134217728);    // 16,777,216
  ushort* S_bf  = (ushort*)(ws + 150994944);    // 8,388,608
  float*  Mp_f32= (float*) (ws + 159383552);    // 16,777,216
  ushort* Mp_bf = (ushort*)(ws + 176160768);    // 8,388,608
  float*  Mq_f32= (float*) (ws + 184549376);    // 262,144
  ushort* Mq_bf = (ushort*)(ws + 184811520);    // 131,072
  float*  Ubuf  = (float*) (ws + 184942592);    // 3,200,000
  float*  BsmB  = (float*) (ws + 188142592);    // 3,200,000
  float*  B1s   = (float*) (ws + 191342592);    // 2,048,000
  float*  B2s   = (float*) (ws + 193390592);    // 2,048,000
  float*  B1m   = (float*) (ws + 195438592);    // 204,800
  float*  B2m   = (float*) (ws + 195643392);    // 204,800
  float*  EPWP  = (float*) (ws + 195848192);    // 64,000
  float*  EQWQ  = (float*) (ws + 195912192);    // 800
  ushort* Wpool = (ushort*)(ws + 195913216);    // 19,660,800 (ends ~205.6 MB)

  // -------- weight conversion --------
  CvtArgs ca;
  const float* wsrc[19] = {hwt1w, hwg1w, hwt2w, hwg2w, slw,
                           encsW[0], encsW[2], encsW[6], encsW[8],
                           encqW[0], encqW[2], encqW[6], encqW[8],
                           encpW[0], encpW[2], encpW[6], encpW[8],
                           modqw, modpw};
  const int wlen[19] = {1048576, 1048576, 1048576, 1048576, 262144,
                        393216, 131072, 524288, 524288,
                        393216, 131072, 524288, 524288,
                        393216, 131072, 524288, 524288,
                        327680, 327680};
  i64 woff[19];
  {
    i64 o = 0;
    for (int i = 0; i < 19; ++i) { ca.src[i] = wsrc[i]; ca.len[i] = wlen[i]; woff[i] = o; o += wlen[i]; }
  }
  k_cvt<<<dim3(9600), dim3(256), 0, stream>>>(ca, Wpool);
  ushort* WhT1 = Wpool + woff[0];
  ushort* WhG1 = Wpool + woff[1];
  ushort* WhT2 = Wpool + woff[2];
  ushort* WhG2 = Wpool + woff[3];
  ushort* WslB = Wpool + woff[4];
  ushort* WencB[3][4];  // [enc][attn,out,ff1,ff2]
  for (int e = 0; e < 3; ++e)
    for (int k = 0; k < 4; ++k) WencB[e][k] = Wpool + woff[5 + e * 4 + k];
  ushort* WmodqB = Wpool + woff[17];
  ushort* WmodpB = Wpool + woff[18];

  // -------- 1. concat -> bf16 --------
  k_concat<<<dim3(NTOK * EMB / 4 / 256), dim3(256), 0, stream>>>(e_q, c_q, e_p, c_p, Xbf);

  // -------- 2. highway (MFMA t/g GEMMs + combine) --------
  {
    dim3 g(8, 127);
    k_gemm<1, false, true><<<g, 256, 0, stream>>>(Xbf, WhT1, hwt1b, nullptr, Tb, NTOK, 1024, 1024);
    k_gemm<3, false, true><<<g, 256, 0, stream>>>(Xbf, WhG1, hwg1b, nullptr, Gb, NTOK, 1024, 1024);
    k_hwcomb<<<dim3(8100), dim3(256), 0, stream>>>(Tb, Gb, Xbf, Hbf);
    k_gemm<1, false, true><<<g, 256, 0, stream>>>(Hbf, WhT2, hwt2b, nullptr, Tb, NTOK, 1024, 1024);
    k_gemm<3, false, true><<<g, 256, 0, stream>>>(Hbf, WhG2, hwg2b, nullptr, Gb, NTOK, 1024, 1024);
    k_hwcomb<<<dim3(8100), dim3(256), 0, stream>>>(Tb, Gb, Hbf, H2bf);
  }

  // -------- 3. shared linear -> S (fp32 + bf16) --------
  k_gemm<0, true, true><<<dim3(2, 127), 256, 0, stream>>>(H2bf, WslB, slb, S_f32, S_bf, NTOK, 256, 1024);

  // -------- encoder helper --------
  struct AttnSpec { int nseq, S, base; const int* lens; };
  auto enc = [&](float* stF, ushort* stB, int M, const float* const* w, ushort* const* wb,
                 const AttnSpec* specs, int nspec) {
    int gy = (M + 127) / 128;
    for (int l = 0; l < 2; ++l) {
      k_gemm<0, false, true><<<dim3(6, gy), 256, 0, stream>>>(
          stB, wb[0] + (i64)l * 3 * HD * HD, w[1] + l * 3 * HD, nullptr, qkvB, M, 768, 256);
      for (int s = 0; s < nspec; ++s)
        k_attn<<<dim3(specs[s].nseq * NHEADS), dim3(256), 0, stream>>>(
            qkvB, attnO, specs[s].lens, specs[s].S, specs[s].base);
      k_gemm<0, true, false><<<dim3(2, gy), 256, 0, stream>>>(
          attnO, wb[1] + (i64)l * HD * HD, w[3] + l * HD, t1, nullptr, M, 256, 256);
      k_lnres<<<dim3(M), dim3(64), 0, stream>>>(stF, stB, t1, w[4] + l * HD, w[5] + l * HD);
      k_gemm<2, false, true><<<dim3(8, gy), 256, 0, stream>>>(
          stB, wb[2] + (i64)l * DFF * HD, w[7] + l * DFF, nullptr, ffB, M, 1024, 256);
      k_gemm<0, true, false><<<dim3(2, gy), 256, 0, stream>>>(
          ffB, wb[3] + (i64)l * HD * DFF, w[9] + l * HD, t1, nullptr, M, 256, 1024);
      k_lnres<<<dim3(M), dim3(64), 0, stream>>>(stF, stB, t1, w[10] + l * HD, w[11] + l * HD);
    }
  };

  // -------- 4. shared encoder --------
  AttnSpec specs[2] = {{NB, QLEN, 0, qlen}, {NB * NPAS, PLEN, NTOKQ, slen}};
  enc(S_f32, S_bf, NTOK, encsW, WencB[0], specs, 2);

  // -------- 5. dual attention (fp32) --------
  k_rowdot<<<dim3(NTOKP), dim3(64), 0, stream>>>(S_f32 + (i64)NTOKQ * HD, dualw, EPWP);
  k_rowdot<<<dim3(NTOKQ), dim3(64), 0, stream>>>(S_f32, dualw + HD, EQWQ);
  k_u<<<dim3(NB * NPAS), dim3(256), 0, stream>>>(S_f32, dualw, EPWP, EQWQ, Ubuf);
  k_softmax_col<<<dim3(500), dim3(256), 0, stream>>>(Ubuf, BsmB);
  k_softmax_row<<<dim3(4000), dim3(256), 0, stream>>>(Ubuf);
  k_aX<<<dim3(NB * NPAS), dim3(256), 0, stream>>>(S_f32, 0, Ubuf, A1s);
  k_bX<<<dim3(NB * NPAS), dim3(256), 0, stream>>>(S_f32 + (i64)NTOKQ * HD, BsmB, B1s);
  k_aX<<<dim3(NB * NPAS), dim3(256), 0, stream>>>(B1s, 1, Ubuf, A2s);
  k_bX<<<dim3(NB * NPAS), dim3(256), 0, stream>>>(A1s, BsmB, B2s);
  k_maxk<<<dim3(200), dim3(256), 0, stream>>>(B1s, B1m);
  k_maxk<<<dim3(200), dim3(256), 0, stream>>>(B2s, B2m);

  // -------- 6. G build + mod projections (MFMA) --------
  k_gbuild<<<dim3(4000), dim3(256), 0, stream>>>(S_f32 + (i64)NTOKQ * HD, A1s, A2s, GpB, NTOKP);
  k_gemm<0, true, true><<<dim3(2, 125), 256, 0, stream>>>(GpB, WmodpB, modpb, Mp_f32, Mp_bf, NTOKP, 256, 1280);
  k_gbuild<<<dim3(50), dim3(256), 0, stream>>>(S_f32, B1m, B2m, GqB, NTOKQ);
  k_gemm<0, true, true><<<dim3(2, 2), 256, 0, stream>>>(GqB, WmodqB, modqb, Mq_f32, Mq_bf, NTOKQ, 256, 1280);

  // -------- 7. model encoders --------
  AttnSpec sp2 = {NB * NPAS, PLEN, 0, slen};
  enc(Mp_f32, Mp_bf, NTOKP, encpW, WencB[2], &sp2, 1);
  AttnSpec sq2 = {NB, QLEN, 0, qlen};
  enc(Mq_f32, Mq_bf, NTOKQ, encqW, WencB[1], &sq2, 1);

  // -------- 8. outputs --------
  k_beta<<<dim3(NB * NPAS), dim3(64), 0, stream>>>(Mp_f32, rankw, out + OFF_BETA);
  k_prob<<<dim3(NB), dim3(64), 0, stream>>>(Mp_f32, answ, out + OFF_PROB);
  k_copy4<<<dim3(50), dim3(256), 0, stream>>>(Mq_f32, out + OFF_MQ, NTOKQ * HD / 4);
  k_copy4<<<dim3(4000), dim3(256), 0, stream>>>(Mp_f32, out + OFF_MP, NTOKP * HD / 4);
  k_masks<<<dim3(63), dim3(256), 0, stream>>>(qlen, slen, out);
}

// Round 4
// 2705.354 us; speedup vs baseline: 3.1276x; 1.4758x over previous
//
#include <hip/hip_runtime.h>
#include <math.h>

typedef long long i64;
typedef __attribute__((ext_vector_type(8))) short short8;
typedef __attribute__((ext_vector_type(4))) float f32x4;

#define NB 4
#define NPAS 10
#define PLEN 400
#define QLEN 50
#define EDIM 256
#define CDIM 768
#define EMB 1024
#define HD 256
#define NHEADS 8
#define DH 32
#define DFF 1024
#define NTOKQ (NB*QLEN)        // 200
#define NTOKP (NB*NPAS*PLEN)   // 16000
#define NTOK  (NTOKQ+NTOKP)    // 16200
#define ATT_SCALE 0.17677669529663687f

// output offsets (floats)
#define OFF_BETA 0
#define OFF_PROB 40
#define OFF_MQ   44
#define OFF_QM   51244
#define OFF_MP   51444
#define OFF_PM   4147444

__device__ __forceinline__ float wsum(float v) {
#pragma unroll
  for (int o = 32; o > 0; o >>= 1) v += __shfl_xor(v, o);
  return v;
}
__device__ __forceinline__ float wmax(float v) {
#pragma unroll
  for (int o = 32; o > 0; o >>= 1) v = fmaxf(v, __shfl_xor(v, o));
  return v;
}
__device__ __forceinline__ float b2f(ushort u) { return __uint_as_float(((unsigned)u) << 16); }
__device__ __forceinline__ ushort f2b(float f) {
  unsigned u = __float_as_uint(f);
  return (ushort)((u + 0x7fffu + ((u >> 16) & 1u)) >> 16);
}
__device__ __forceinline__ void st_bf4(ushort* p, float a, float b, float c, float d) {
  ushort4 o = {f2b(a), f2b(b), f2b(c), f2b(d)};
  *(ushort4*)p = o;
}

// ---------------- weight fp32->bf16 conversion (19 arrays, one kernel) ----------------
struct CvtArgs { const float* src[19]; int len[19]; };
__global__ void k_cvt(CvtArgs a, ushort* __restrict__ dst) {
  i64 pos = ((i64)blockIdx.x * 256 + threadIdx.x) * 4;
  i64 off = 0; int s = 0;
#pragma unroll 1
  for (; s < 19; ++s) { if (pos < off + a.len[s]) break; off += a.len[s]; }
  if (s >= 19) return;
  float4 v = *(const float4*)(a.src[s] + (pos - off));
  st_bf4(dst + pos, v.x, v.y, v.z, v.w);
}

// ---------------- concat [e|c] -> X bf16 (NTOK x EMB) ----------------
__global__ void k_concat(const float* __restrict__ eq, const float* __restrict__ cq,
                         const float* __restrict__ ep, const float* __restrict__ cp,
                         ushort* __restrict__ X) {
  int idx = blockIdx.x * 256 + threadIdx.x;   // 4-elem index, grid exact
  i64 e = (i64)idx * 4;
  int row = (int)(e / EMB), c = (int)(e % EMB);
  float4 v;
  if (row < NTOKQ) {
    if (c < EDIM) v = *(const float4*)(eq + (i64)row * EDIM + c);
    else          v = *(const float4*)(cq + (i64)row * CDIM + (c - EDIM));
  } else {
    int t = row - NTOKQ;
    if (c < EDIM) v = *(const float4*)(ep + (i64)t * EDIM + c);
    else          v = *(const float4*)(cp + (i64)t * CDIM + (c - EDIM));
  }
  st_bf4(X + (i64)row * EMB + c, v.x, v.y, v.z, v.w);
}

// ---------------- MFMA bf16 GEMM: C = A(MxK) @ W(NxK)^T + b ----------------
// ACT: 0 none, 1 relu, 2 gelu, 3 sigmoid. Dual-output fp32/bf16.
template <int ACT, bool WF32, bool WBF>
__global__ __launch_bounds__(256) void k_gemm(const ushort* __restrict__ A,
                                              const ushort* __restrict__ W,
                                              const float* __restrict__ bias,
                                              float* __restrict__ Cf,
                                              ushort* __restrict__ Cb,
                                              int M, int N, int K) {
  __shared__ ushort Al[128 * 64];
  __shared__ ushort Bl[128 * 64];
  const int tid = threadIdx.x;
  const int lane = tid & 63;
  const int wave = tid >> 6;
  const int wm = wave >> 1, wn = wave & 1;
  const int r0 = blockIdx.y * 128, c0 = blockIdx.x * 128;
  const int srow = tid >> 3;      // 0..31 (+ch*32)
  const int scol = tid & 7;       // 16B slot within 128B row
  f32x4 acc[4][4] = {};
  short8 Asr[4], Bsr[4];
#pragma unroll
  for (int ch = 0; ch < 4; ++ch) {
    int row = ch * 32 + srow;
    Asr[ch] = *(const short8*)(A + (i64)(r0 + row) * K + scol * 8);
    Bsr[ch] = *(const short8*)(W + (i64)(c0 + row) * K + scol * 8);
  }
  const int nk = K >> 6;
  for (int kt = 0; kt < nk; ++kt) {
#pragma unroll
    for (int ch = 0; ch < 4; ++ch) {
      int row = ch * 32 + srow;
      int slot = scol ^ (row & 7);
      *(short8*)(Al + row * 64 + slot * 8) = Asr[ch];
      *(short8*)(Bl + row * 64 + slot * 8) = Bsr[ch];
    }
    __syncthreads();
    if (kt + 1 < nk) {
      int k0 = (kt + 1) << 6;
#pragma unroll
      for (int ch = 0; ch < 4; ++ch) {
        int row = ch * 32 + srow;
        Asr[ch] = *(const short8*)(A + (i64)(r0 + row) * K + k0 + scol * 8);
        Bsr[ch] = *(const short8*)(W + (i64)(c0 + row) * K + k0 + scol * 8);
      }
    }
#pragma unroll
    for (int ks = 0; ks < 2; ++ks) {
      short8 af[4], bf[4];
      int c16 = ks * 4 + (lane >> 4);
#pragma unroll
      for (int m = 0; m < 4; ++m) {
        int arow = wm * 64 + m * 16 + (lane & 15);
        af[m] = *(const short8*)(Al + arow * 64 + ((c16 ^ (arow & 7)) * 8));
        int brow = wn * 64 + m * 16 + (lane & 15);
        bf[m] = *(const short8*)(Bl + brow * 64 + ((c16 ^ (brow & 7)) * 8));
      }
#pragma unroll
      for (int m = 0; m < 4; ++m)
#pragma unroll
        for (int n = 0; n < 4; ++n)
          acc[m][n] = __builtin_amdgcn_mfma_f32_16x16x32_bf16(af[m], bf[n], acc[m][n], 0, 0, 0);
    }
    __syncthreads();
  }
#pragma unroll
  for (int m = 0; m < 4; ++m) {
    int row = r0 + wm * 64 + m * 16 + (lane >> 4) * 4;
#pragma unroll
    for (int n = 0; n < 4; ++n) {
      int col = c0 + wn * 64 + n * 16 + (lane & 15);
      float bv = bias[col];
#pragma unroll
      for (int j = 0; j < 4; ++j) {
        if (row + j >= M) continue;
        float v = acc[m][n][j] + bv;
        if (ACT == 1) v = fmaxf(v, 0.f);
        if (ACT == 2) v = 0.5f * v * (1.f + erff(v * 0.70710678118f));
        if (ACT == 3) v = 1.f / (1.f + __expf(-v));
        if (WF32) Cf[(i64)(row + j) * N + col] = v;
        if (WBF)  Cb[(i64)(row + j) * N + col] = f2b(v);
      }
    }
  }
}

// ---------------- highway combine: h = g*t + (1-g)*x (all bf16) ----------------
__global__ void k_hwcomb(const ushort* __restrict__ T, const ushort* __restrict__ G,
                         const ushort* __restrict__ X, ushort* __restrict__ H) {
  i64 o = ((i64)blockIdx.x * 256 + threadIdx.x) * 8;
  ushort tb[8], gb[8], xb[8], hb[8];
  *(uint4*)tb = *(const uint4*)(T + o);
  *(uint4*)gb = *(const uint4*)(G + o);
  *(uint4*)xb = *(const uint4*)(X + o);
#pragma unroll
  for (int i = 0; i < 8; ++i) {
    float t = b2f(tb[i]), g = b2f(gb[i]), x = b2f(xb[i]);
    hb[i] = f2b(g * t + (1.f - g) * x);
  }
  *(uint4*)(H + o) = *(uint4*)hb;
}

// ---------------- residual + layernorm, fp32 state + bf16 copy ----------------
__global__ void k_lnres(float* __restrict__ X, ushort* __restrict__ Xb,
                        const float* __restrict__ Hh,
                        const float* __restrict__ g, const float* __restrict__ b) {
  int row = blockIdx.x;
  int lane = threadIdx.x;
  float4 xv = *(float4*)(X + (i64)row * HD + lane * 4);
  float4 hv = *(const float4*)(Hh + (i64)row * HD + lane * 4);
  float v0 = xv.x + hv.x, v1 = xv.y + hv.y, v2 = xv.z + hv.z, v3 = xv.w + hv.w;
  float m = wsum(v0 + v1 + v2 + v3) * (1.f / HD);
  float d0 = v0 - m, d1 = v1 - m, d2 = v2 - m, d3 = v3 - m;
  float var = wsum(d0 * d0 + d1 * d1 + d2 * d2 + d3 * d3) * (1.f / HD);
  float rstd = rsqrtf(var + 1e-5f);
  float4 gv = *(const float4*)(g + lane * 4);
  float4 bv = *(const float4*)(b + lane * 4);
  float4 o;
  o.x = d0 * rstd * gv.x + bv.x;
  o.y = d1 * rstd * gv.y + bv.y;
  o.z = d2 * rstd * gv.z + bv.z;
  o.w = d3 * rstd * gv.w + bv.w;
  *(float4*)(X + (i64)row * HD + lane * 4) = o;
  st_bf4(Xb + (i64)row * HD + lane * 4, o.x, o.y, o.z, o.w);
}

// ---------------- MHA: fp32 qkv in, bf16 O out. Block = (seq,head,chunk of 256 rows) ----------------
template <int S>
__global__ __launch_bounds__(256) void k_attn2(const float* __restrict__ qkv,
                                               ushort* __restrict__ O,
                                               const int* __restrict__ lens,
                                               int tokBase) {
  __shared__ float Ks[S * DH];
  int sh = blockIdx.x;
  int seq = sh >> 3, head = sh & 7;
  int len = lens[seq];
  int base = tokBase + seq * S;
  const float* Qp = qkv + (i64)base * 768 + head * DH;
  for (int idx = threadIdx.x; idx < S * DH / 4; idx += 256) {
    int t = idx >> 3, c = idx & 7;
    *(float4*)(Ks + t * DH + c * 4) = *(const float4*)(Qp + 256 + (i64)t * 768 + c * 4);
  }
  __syncthreads();
  int r = blockIdx.y * 256 + threadIdx.x;
  if (r >= S) return;
  float q[DH];
#pragma unroll
  for (int c = 0; c < 8; ++c) {
    float4 qv = *(const float4*)(Qp + (i64)r * 768 + c * 4);
    q[c * 4] = qv.x; q[c * 4 + 1] = qv.y; q[c * 4 + 2] = qv.z; q[c * 4 + 3] = qv.w;
  }
  float mx = -1e30f, l = 0.f, acc[DH] = {};
  const float* Vp = Qp + 512;
  int lmain = len & ~7;
  for (int j0 = 0; j0 < lmain; j0 += 8) {
    float s[8];
#pragma unroll
    for (int i = 0; i < 8; ++i) {
      float d = 0.f;
#pragma unroll
      for (int c = 0; c < 8; ++c) {
        float4 kv = *(const float4*)(Ks + (j0 + i) * DH + c * 4);
        d += q[c * 4] * kv.x + q[c * 4 + 1] * kv.y + q[c * 4 + 2] * kv.z + q[c * 4 + 3] * kv.w;
      }
      s[i] = d * ATT_SCALE;
    }
    float m8 = fmaxf(fmaxf(fmaxf(s[0], s[1]), fmaxf(s[2], s[3])),
                     fmaxf(fmaxf(s[4], s[5]), fmaxf(s[6], s[7])));
    float mn = fmaxf(mx, m8);
    float corr = __expf(mx - mn);
    l *= corr;
#pragma unroll
    for (int d = 0; d < DH; ++d) acc[d] *= corr;
#pragma unroll
    for (int i = 0; i < 8; ++i) {
      float e = __expf(s[i] - mn);
      l += e;
      const float* vr = Vp + (i64)(j0 + i) * 768;
#pragma unroll
      for (int c = 0; c < 8; ++c) {
        float4 vv = *(const float4*)(vr + c * 4);
        acc[c * 4] += e * vv.x; acc[c * 4 + 1] += e * vv.y;
        acc[c * 4 + 2] += e * vv.z; acc[c * 4 + 3] += e * vv.w;
      }
    }
    mx = mn;
  }
  for (int j = lmain; j < len; ++j) {
    float d = 0.f;
#pragma unroll
    for (int c = 0; c < 8; ++c) {
      float4 kv = *(const float4*)(Ks + j * DH + c * 4);
      d += q[c * 4] * kv.x + q[c * 4 + 1] * kv.y + q[c * 4 + 2] * kv.z + q[c * 4 + 3] * kv.w;
    }
    d *= ATT_SCALE;
    float mn = fmaxf(mx, d);
    float corr = __expf(mx - mn);
    float e = __expf(d - mn);
    l = l * corr + e;
    const float* vr = Vp + (i64)j * 768;
#pragma unroll
    for (int c = 0; c < 8; ++c) {
      float4 vv = *(const float4*)(vr + c * 4);
      acc[c * 4] = acc[c * 4] * corr + e * vv.x;
      acc[c * 4 + 1] = acc[c * 4 + 1] * corr + e * vv.y;
      acc[c * 4 + 2] = acc[c * 4 + 2] * corr + e * vv.z;
      acc[c * 4 + 3] = acc[c * 4 + 3] * corr + e * vv.w;
    }
    mx = mn;
  }
  float inv = 1.f / l;
  ushort* op = O + (i64)(base + r) * HD + head * DH;
#pragma unroll
  for (int c = 0; c < 8; ++c)
    st_bf4(op + c * 4, acc[c * 4] * inv, acc[c * 4 + 1] * inv,
           acc[c * 4 + 2] * inv, acc[c * 4 + 3] * inv);
}

// ---------------- row dot with weight vector (len HD) ----------------
__global__ void k_rowdot(const float* __restrict__ X, const float* __restrict__ w,
                         float* __restrict__ out) {
  int row = blockIdx.x;
  int lane = threadIdx.x;
  float4 x = *(const float4*)(X + (i64)row * HD + lane * 4);
  float4 wv = *(const float4*)(w + lane * 4);
  float s = wsum(x.x * wv.x + x.y * wv.y + x.z * wv.z + x.w * wv.w);
  if (lane == 0) out[row] = s;
}

// ---------------- U tile: block = (bk, ptile of 16) ----------------
__global__ __launch_bounds__(256) void k_u2(const float* __restrict__ E,
                                            const float* __restrict__ dual,
                                            const float* __restrict__ epwp,
                                            const float* __restrict__ eqwq,
                                            float* __restrict__ U) {
  __shared__ float Eqx[QLEN][260];   // 52 KB, 16B-aligned rows
  int bk = blockIdx.x, pt = blockIdx.y, b = bk / NPAS;
  for (int idx = threadIdx.x; idx < QLEN * 64; idx += 256) {
    int q = idx >> 6, h4 = idx & 63;
    float4 ev = *(const float4*)(E + (i64)(b * QLEN + q) * HD + h4 * 4);
    float4 dv = *(const float4*)(dual + 2 * HD + h4 * 4);
    *(float4*)(&Eqx[q][h4 * 4]) = make_float4(ev.x * dv.x, ev.y * dv.y, ev.z * dv.z, ev.w * dv.w);
  }
  __syncthreads();
  int pi = threadIdx.x >> 4, qi = threadIdx.x & 15;
  int p = pt * 16 + pi;
  const float* ep = E + (i64)(NTOKQ + bk * PLEN + p) * HD;
  float acc[4] = {};
#pragma unroll 4
  for (int h4 = 0; h4 < 64; ++h4) {
    float4 e4 = *(const float4*)(ep + h4 * 4);
#pragma unroll
    for (int m = 0; m < 4; ++m) {
      int q = qi + m * 16;
      int qq = q < QLEN ? q : QLEN - 1;
      float4 x4 = *(const float4*)(&Eqx[qq][h4 * 4]);
      acc[m] += e4.x * x4.x + e4.y * x4.y + e4.z * x4.z + e4.w * x4.w;
    }
  }
  float pw = epwp[bk * PLEN + p];
#pragma unroll
  for (int m = 0; m < 4; ++m) {
    int q = qi + m * 16;
    if (q < QLEN)
      U[(i64)(bk * PLEN + p) * QLEN + q] = pw + eqwq[b * QLEN + q] + acc[m];
  }
}

// ---------------- Bsm: softmax over p (column) ----------------
__global__ void k_softmax_col(const float* __restrict__ U, float* __restrict__ Bsm) {
  int col = blockIdx.x * 4 + (threadIdx.x >> 6);  // 2000 columns
  int lane = threadIdx.x & 63;
  int bk = col / QLEN, q = col % QLEN;
  const float* Ucol = U + (i64)bk * PLEN * QLEN + q;
  float v[7];
#pragma unroll
  for (int i = 0; i < 7; ++i) {
    int p = lane + i * 64;
    v[i] = (p < PLEN) ? Ucol[(i64)p * QLEN] : -1e30f;
  }
  float m = v[0];
#pragma unroll
  for (int i = 1; i < 7; ++i) m = fmaxf(m, v[i]);
  m = wmax(m);
  float s = 0.f;
#pragma unroll
  for (int i = 0; i < 7; ++i) {
    int p = lane + i * 64;
    v[i] = (p < PLEN) ? __expf(v[i] - m) : 0.f;
    s += v[i];
  }
  s = wsum(s);
  float inv = 1.f / s;
#pragma unroll
  for (int i = 0; i < 7; ++i) {
    int p = lane + i * 64;
    if (p < PLEN) Bsm[(i64)bk * PLEN * QLEN + (i64)p * QLEN + q] = v[i] * inv;
  }
}

// ---------------- Asm: row softmax in place ----------------
__global__ void k_softmax_row(float* __restrict__ U) {
  int row = blockIdx.x * 4 + (threadIdx.x >> 6);
  int lane = threadIdx.x & 63;
  float v = (lane < QLEN) ? U[(i64)row * QLEN + lane] : -1e30f;
  float m = wmax(v);
  float e = (lane < QLEN) ? __expf(v - m) : 0.f;
  float s = wsum(e);
  if (lane < QLEN) U[(i64)row * QLEN + lane] = e / s;
}

// ---------------- A-type: block = (bk, ptile of 16); thread = h ----------------
__global__ __launch_bounds__(256) void k_aX2(const float* __restrict__ inQ, int strideSel,
                                             const float* __restrict__ Asm,
                                             float* __restrict__ out) {
  int bk = blockIdx.x, pt = blockIdx.y, b = bk / NPAS;
  const float* in = inQ + (i64)(strideSel ? bk : b) * QLEN * HD;
  __shared__ float AsmL[16][52];
  int tid = threadIdx.x;
  for (int idx = tid; idx < 16 * QLEN; idx += 256)
    AsmL[idx / QLEN][idx % QLEN] = Asm[(i64)(bk * PLEN + pt * 16) * QLEN + idx];
  __syncthreads();
  float inr[QLEN];
#pragma unroll
  for (int q = 0; q < QLEN; ++q) inr[q] = in[(i64)q * HD + tid];
#pragma unroll 2
  for (int pl = 0; pl < 16; ++pl) {
    float a0 = 0.f, a1 = 0.f;
#pragma unroll
    for (int q = 0; q < QLEN; q += 2) { a0 += inr[q] * AsmL[pl][q]; a1 += inr[q + 1] * AsmL[pl][q + 1]; }
    out[(i64)(bk * PLEN + pt * 16 + pl) * HD + tid] = a0 + a1;
  }
}

// ---------------- B-type: block = (bk, qtile of 5); thread = h ----------------
__global__ __launch_bounds__(256) void k_bX2(const float* __restrict__ inP,
                                             const float* __restrict__ Bsm,
                                             float* __restrict__ out) {
  int bk = blockIdx.x, qt = blockIdx.y;  // q = qt*5 .. +4
  const float* in = inP + (i64)bk * PLEN * HD;
  __shared__ float BsmL[PLEN][5];
  int tid = threadIdx.x;
  for (int idx = tid; idx < PLEN * 5; idx += 256) {
    int p = idx / 5, m = idx % 5;
    BsmL[p][m] = Bsm[(i64)(bk * PLEN + p) * QLEN + qt * 5 + m];
  }
  __syncthreads();
  float acc[5] = {};
  for (int p = 0; p < PLEN; ++p) {
    float e = in[(i64)p * HD + tid];
#pragma unroll
    for (int m = 0; m < 5; ++m) acc[m] += e * BsmL[p][m];
  }
#pragma unroll
  for (int m = 0; m < 5; ++m)
    out[(i64)(bk * QLEN + qt * 5 + m) * HD + tid] = acc[m];
}

// ---------------- max over k ----------------
__global__ void k_maxk(const float* __restrict__ Bs, float* __restrict__ Bm) {
  int idx = blockIdx.x * 256 + threadIdx.x;
  if (idx >= NB * QLEN * HD) return;
  int b = idx / (QLEN * HD), r = idx % (QLEN * HD);
  float m = -1e30f;
#pragma unroll
  for (int k = 0; k < NPAS; ++k) m = fmaxf(m, Bs[(i64)(b * NPAS + k) * QLEN * HD + r]);
  Bm[idx] = m;
}

// ---------------- G build: [ep | x1 | x2 | ep*x1 | ep*x2] bf16, K=1280 ----------------
__global__ void k_gbuild(const float* __restrict__ E, const float* __restrict__ x1,
                         const float* __restrict__ x2, ushort* __restrict__ Gt, int ntok) {
  int tok = blockIdx.x * 4 + (threadIdx.x >> 6);
  int h4 = (threadIdx.x & 63) * 4;
  if (tok >= ntok) return;
  float4 ep = *(const float4*)(E + (i64)tok * HD + h4);
  float4 a1 = *(const float4*)(x1 + (i64)tok * HD + h4);
  float4 a2 = *(const float4*)(x2 + (i64)tok * HD + h4);
  ushort* g = Gt + (i64)tok * 1280;
  st_bf4(g + h4, ep.x, ep.y, ep.z, ep.w);
  st_bf4(g + 256 + h4, a1.x, a1.y, a1.z, a1.w);
  st_bf4(g + 512 + h4, a2.x, a2.y, a2.z, a2.w);
  st_bf4(g + 768 + h4, ep.x * a1.x, ep.y * a1.y, ep.z * a1.z, ep.w * a1.w);
  st_bf4(g + 1024 + h4, ep.x * a2.x, ep.y * a2.y, ep.z * a2.z, ep.w * a2.w);
}

// ---------------- outputs ----------------
__global__ void k_beta(const float* __restrict__ Mp, const float* __restrict__ rw,
                       float* __restrict__ outv) {
  int bk = blockIdx.x;
  int lane = threadIdx.x;
  const float* m1 = Mp + (i64)bk * PLEN * HD;
  float4 x = *(const float4*)(m1 + lane * 4);
  float4 w = *(const float4*)(rw + lane * 4);
  float s = wsum(x.x * w.x + x.y * w.y + x.z * w.z + x.w * w.w);
  if (lane == 0) outv[bk] = 1.f / (1.f + __expf(-s));
}

__global__ void k_prob(const float* __restrict__ Mp, const float* __restrict__ aw,
                       float* __restrict__ outv) {
  int b = blockIdx.x;
  int lane = threadIdx.x;
  float s = 0.f;
#pragma unroll
  for (int k = 0; k < NPAS; ++k) {
    const float* m1 = Mp + (i64)(b * NPAS + k) * PLEN * HD;
    float4 x = *(const float4*)(m1 + lane * 4);
    float4 w = *(const float4*)(aw + (i64)k * HD + lane * 4);
    s += x.x * w.x + x.y * w.y + x.z * w.z + x.w * w.w;
  }
  s = wsum(s);
  if (lane == 0) outv[b] = 1.f / (1.f + __expf(-s));
}

__global__ void k_masks(const int* __restrict__ qlen, const int* __restrict__ slen,
                        float* __restrict__ out) {
  int idx = blockIdx.x * 256 + threadIdx.x;
  if (idx < NTOKQ) {
    int b = idx / QLEN, i = idx % QLEN;
    out[OFF_QM + idx] = (i >= qlen[b]) ? 1.f : 0.f;
  }
  if (idx < NTOKP) {
    int s = idx / PLEN, i = idx % PLEN;
    out[OFF_PM + idx] = (i >= slen[s]) ? 1.f : 0.f;
  }
}

__global__ void k_copy4(const float* __restrict__ src, float* __restrict__ dst, int n4) {
  int idx = blockIdx.x * 256 + threadIdx.x;
  if (idx < n4) ((float4*)dst)[idx] = ((const float4*)src)[idx];
}

// =======================================================================
extern "C" void kernel_launch(void* const* d_in, const int* in_sizes, int n_in,
                              void* d_out, int out_size, void* d_ws, size_t ws_size,
                              hipStream_t stream) {
  const float* e_q = (const float*)d_in[0];
  const float* c_q = (const float*)d_in[1];
  const float* e_p = (const float*)d_in[2];
  const float* c_p = (const float*)d_in[3];
  const int* qlen = (const int*)d_in[4];
  const int* slen = (const int*)d_in[5];
  const float* hwt1w = (const float*)d_in[6];
  const float* hwt1b = (const float*)d_in[7];
  const float* hwg1w = (const float*)d_in[8];
  const float* hwg1b = (const float*)d_in[9];
  const float* hwt2w = (const float*)d_in[10];
  const float* hwt2b = (const float*)d_in[11];
  const float* hwg2w = (const float*)d_in[12];
  const float* hwg2b = (const float*)d_in[13];
  const float* slw = (const float*)d_in[14];
  const float* slb = (const float*)d_in[15];
  const float* encsW[12];
  const float* encqW[12];
  const float* encpW[12];
  for (int i = 0; i < 12; ++i) {
    encsW[i] = (const float*)d_in[16 + i];
    encqW[i] = (const float*)d_in[28 + i];
    encpW[i] = (const float*)d_in[40 + i];
  }
  const float* dualw = (const float*)d_in[52];
  const float* modqw = (const float*)d_in[53];
  const float* modqb = (const float*)d_in[54];
  const float* modpw = (const float*)d_in[55];
  const float* modpb = (const float*)d_in[56];
  const float* rankw = (const float*)d_in[57];
  const float* answ = (const float*)d_in[58];
  float* out = (float*)d_out;

  // -------- workspace layout (byte offsets) --------
  char* ws = (char*)d_ws;
  // ES region [0, 67,108,864): time-disjoint scratch
  float*  qkvF  = (float*) (ws + 0);            // 16384x768 f32 = 50,331,648
  ushort* attnO = (ushort*)(ws + 50331648);     // 16384x256 bf16 = 8,388,608 (ends 58,720,256)
  float*  t1    = (float*) (ws + 0);            // 16384x256 f32 (aliases qkvF; qkvF dead by then)
  ushort* ffB   = (ushort*)(ws + 16777216);     // 16384x1024 bf16 (ends 50,331,648)
  ushort* Tb    = (ushort*)(ws + 0);            // highway T
  ushort* Gb    = (ushort*)(ws + 33554432);     // highway G (ends 67,108,864)
  ushort* GpB   = (ushort*)(ws + 0);            // 16384x1280 bf16 = 41,943,040
  ushort* GqB   = (ushort*)(ws + 44040192);     // 256x1280 bf16
  // RA / RB
  ushort* Xbf   = (ushort*)(ws + 67108864);     // 16384x1024 bf16
  ushort* H2bf  = Xbf;
  ushort* Hbf   = (ushort*)(ws + 100663296);
  float*  A1s   = (float*) (ws + 100663296);    // 16,384,000
  float*  A2s   = (float*) (ws + 117047296);    // 16,384,000
  // persistent states
  float*  S_f32 = (float*) (ws + 134217728);
  ushort* S_bf  = (ushort*)(ws + 150994944);
  float*  Mp_f32= (float*) (ws + 159383552);
  ushort* Mp_bf = (ushort*)(ws + 176160768);
  float*  Mq_f32= (float*) (ws + 184549376);
  ushort* Mq_bf = (ushort*)(ws + 184811520);
  float*  Ubuf  = (float*) (ws + 184942592);
  float*  BsmB  = (float*) (ws + 188142592);
  float*  B1s   = (float*) (ws + 191342592);
  float*  B2s   = (float*) (ws + 193390592);
  float*  B1m   = (float*) (ws + 195438592);
  float*  B2m   = (float*) (ws + 195643392);
  float*  EPWP  = (float*) (ws + 195848192);
  float*  EQWQ  = (float*) (ws + 195912192);
  ushort* Wpool = (ushort*)(ws + 195913216);    // ends ~215.6 MB

  // -------- weight conversion --------
  CvtArgs ca;
  const float* wsrc[19] = {hwt1w, hwg1w, hwt2w, hwg2w, slw,
                           encsW[0], encsW[2], encsW[6], encsW[8],
                           encqW[0], encqW[2], encqW[6], encqW[8],
                           encpW[0], encpW[2], encpW[6], encpW[8],
                           modqw, modpw};
  const int wlen[19] = {1048576, 1048576, 1048576, 1048576, 262144,
                        393216, 131072, 524288, 524288,
                        393216, 131072, 524288, 524288,
                        393216, 131072, 524288, 524288,
                        327680, 327680};
  i64 woff[19];
  {
    i64 o = 0;
    for (int i = 0; i < 19; ++i) { ca.src[i] = wsrc[i]; ca.len[i] = wlen[i]; woff[i] = o; o += wlen[i]; }
  }
  k_cvt<<<dim3(9600), dim3(256), 0, stream>>>(ca, Wpool);
  ushort* WhT1 = Wpool + woff[0];
  ushort* WhG1 = Wpool + woff[1];
  ushort* WhT2 = Wpool + woff[2];
  ushort* WhG2 = Wpool + woff[3];
  ushort* WslB = Wpool + woff[4];
  ushort* WencB[3][4];
  for (int e = 0; e < 3; ++e)
    for (int k = 0; k < 4; ++k) WencB[e][k] = Wpool + woff[5 + e * 4 + k];
  ushort* WmodqB = Wpool + woff[17];
  ushort* WmodpB = Wpool + woff[18];

  // -------- 1. concat -> bf16 --------
  k_concat<<<dim3(NTOK * EMB / 4 / 256), dim3(256), 0, stream>>>(e_q, c_q, e_p, c_p, Xbf);

  // -------- 2. highway --------
  {
    dim3 g(8, 127);
    k_gemm<1, false, true><<<g, 256, 0, stream>>>(Xbf, WhT1, hwt1b, nullptr, Tb, NTOK, 1024, 1024);
    k_gemm<3, false, true><<<g, 256, 0, stream>>>(Xbf, WhG1, hwg1b, nullptr, Gb, NTOK, 1024, 1024);
    k_hwcomb<<<dim3(8100), dim3(256), 0, stream>>>(Tb, Gb, Xbf, Hbf);
    k_gemm<1, false, true><<<g, 256, 0, stream>>>(Hbf, WhT2, hwt2b, nullptr, Tb, NTOK, 1024, 1024);
    k_gemm<3, false, true><<<g, 256, 0, stream>>>(Hbf, WhG2, hwg2b, nullptr, Gb, NTOK, 1024, 1024);
    k_hwcomb<<<dim3(8100), dim3(256), 0, stream>>>(Tb, Gb, Hbf, H2bf);
  }

  // -------- 3. shared linear -> S --------
  k_gemm<0, true, true><<<dim3(2, 127), 256, 0, stream>>>(H2bf, WslB, slb, S_f32, S_bf, NTOK, 256, 1024);

  // -------- encoder helper --------
  struct AttnSpec { int nseq, S, base; const int* lens; };
  auto enc = [&](float* stF, ushort* stB, int M, const float* const* w, ushort* const* wb,
                 const AttnSpec* specs, int nspec) {
    int gy = (M + 127) / 128;
    for (int l = 0; l < 2; ++l) {
      k_gemm<0, true, false><<<dim3(6, gy), 256, 0, stream>>>(
          stB, wb[0] + (i64)l * 3 * HD * HD, w[1] + l * 3 * HD, qkvF, nullptr, M, 768, 256);
      for (int s = 0; s < nspec; ++s) {
        if (specs[s].S == PLEN)
          k_attn2<PLEN><<<dim3(specs[s].nseq * NHEADS, 2), dim3(256), 0, stream>>>(
              qkvF, attnO, specs[s].lens, specs[s].base);
        else
          k_attn2<QLEN><<<dim3(specs[s].nseq * NHEADS, 1), dim3(256), 0, stream>>>(
              qkvF, attnO, specs[s].lens, specs[s].base);
      }
      k_gemm<0, true, false><<<dim3(2, gy), 256, 0, stream>>>(
          attnO, wb[1] + (i64)l * HD * HD, w[3] + l * HD, t1, nullptr, M, 256, 256);
      k_lnres<<<dim3(M), dim3(64), 0, stream>>>(stF, stB, t1, w[4] + l * HD, w[5] + l * HD);
      k_gemm<2, false, true><<<dim3(8, gy), 256, 0, stream>>>(
          stB, wb[2] + (i64)l * DFF * HD, w[7] + l * DFF, nullptr, ffB, M, 1024, 256);
      k_gemm<0, true, false><<<dim3(2, gy), 256, 0, stream>>>(
          ffB, wb[3] + (i64)l * HD * DFF, w[9] + l * HD, t1, nullptr, M, 256, 1024);
      k_lnres<<<dim3(M), dim3(64), 0, stream>>>(stF, stB, t1, w[10] + l * HD, w[11] + l * HD);
    }
  };

  // -------- 4. shared encoder --------
  AttnSpec specs[2] = {{NB, QLEN, 0, qlen}, {NB * NPAS, PLEN, NTOKQ, slen}};
  enc(S_f32, S_bf, NTOK, encsW, WencB[0], specs, 2);

  // -------- 5. dual attention --------
  k_rowdot<<<dim3(NTOKP), dim3(64), 0, stream>>>(S_f32 + (i64)NTOKQ * HD, dualw, EPWP);
  k_rowdot<<<dim3(NTOKQ), dim3(64), 0, stream>>>(S_f32, dualw + HD, EQWQ);
  k_u2<<<dim3(NB * NPAS, 25), dim3(256), 0, stream>>>(S_f32, dualw, EPWP, EQWQ, Ubuf);
  k_softmax_col<<<dim3(500), dim3(256), 0, stream>>>(Ubuf, BsmB);
  k_softmax_row<<<dim3(4000), dim3(256), 0, stream>>>(Ubuf);
  k_aX2<<<dim3(NB * NPAS, 25), dim3(256), 0, stream>>>(S_f32, 0, Ubuf, A1s);
  k_bX2<<<dim3(NB * NPAS, 10), dim3(256), 0, stream>>>(S_f32 + (i64)NTOKQ * HD, BsmB, B1s);
  k_aX2<<<dim3(NB * NPAS, 25), dim3(256), 0, stream>>>(B1s, 1, Ubuf, A2s);
  k_bX2<<<dim3(NB * NPAS, 10), dim3(256), 0, stream>>>(A1s, BsmB, B2s);
  k_maxk<<<dim3(200), dim3(256), 0, stream>>>(B1s, B1m);
  k_maxk<<<dim3(200), dim3(256), 0, stream>>>(B2s, B2m);

  // -------- 6. G build + mod projections --------
  k_gbuild<<<dim3(4000), dim3(256), 0, stream>>>(S_f32 + (i64)NTOKQ * HD, A1s, A2s, GpB, NTOKP);
  k_gemm<0, true, true><<<dim3(2, 125), 256, 0, stream>>>(GpB, WmodpB, modpb, Mp_f32, Mp_bf, NTOKP, 256, 1280);
  k_gbuild<<<dim3(50), dim3(256), 0, stream>>>(S_f32, B1m, B2m, GqB, NTOKQ);
  k_gemm<0, true, true><<<dim3(2, 2), 256, 0, stream>>>(GqB, WmodqB, modqb, Mq_f32, Mq_bf, NTOKQ, 256, 1280);

  // -------- 7. model encoders --------
  AttnSpec sp2 = {NB * NPAS, PLEN, 0, slen};
  enc(Mp_f32, Mp_bf, NTOKP, encpW, WencB[2], &sp2, 1);
  AttnSpec sq2 = {NB, QLEN, 0, qlen};
  enc(Mq_f32, Mq_bf, NTOKQ, encqW, WencB[1], &sq2, 1);

  // -------- 8. outputs --------
  k_beta<<<dim3(NB * NPAS), dim3(64), 0, stream>>>(Mp_f32, rankw, out + OFF_BETA);
  k_prob<<<dim3(NB), dim3(64), 0, stream>>>(Mp_f32, answ, out + OFF_PROB);
  k_copy4<<<dim3(50), dim3(256), 0, stream>>>(Mq_f32, out + OFF_MQ, NTOKQ * HD / 4);
  k_copy4<<<dim3(4000), dim3(256), 0, stream>>>(Mp_f32, out + OFF_MP, NTOKP * HD / 4);
  k_masks<<<dim3(63), dim3(256), 0, stream>>>(qlen, slen, out);
}

// Round 5
// 1619.106 us; speedup vs baseline: 5.2259x; 1.6709x over previous
//
#include <hip/hip_runtime.h>
#include <math.h>

typedef long long i64;
typedef __attribute__((ext_vector_type(8))) short short8;
typedef __attribute__((ext_vector_type(4))) float f32x4;

#define NB 4
#define NPAS 10
#define PLEN 400
#define QLEN 50
#define EDIM 256
#define CDIM 768
#define EMB 1024
#define HD 256
#define NHEADS 8
#define DH 32
#define DFF 1024
#define NTOKQ (NB*QLEN)        // 200
#define NTOKP (NB*NPAS*PLEN)   // 16000
#define NTOK  (NTOKQ+NTOKP)    // 16200
#define ATT_SCALE 0.17677669529663687f

// output offsets (floats)
#define OFF_BETA 0
#define OFF_PROB 40
#define OFF_MQ   44
#define OFF_QM   51244
#define OFF_MP   51444
#define OFF_PM   4147444

__device__ __forceinline__ float wsum(float v) {
#pragma unroll
  for (int o = 32; o > 0; o >>= 1) v += __shfl_xor(v, o);
  return v;
}
__device__ __forceinline__ float wmax(float v) {
#pragma unroll
  for (int o = 32; o > 0; o >>= 1) v = fmaxf(v, __shfl_xor(v, o));
  return v;
}
__device__ __forceinline__ float b2f(ushort u) { return __uint_as_float(((unsigned)u) << 16); }
__device__ __forceinline__ ushort f2b(float f) {
  unsigned u = __float_as_uint(f);
  return (ushort)((u + 0x7fffu + ((u >> 16) & 1u)) >> 16);
}
__device__ __forceinline__ void st_bf4(ushort* p, float a, float b, float c, float d) {
  ushort4 o = {f2b(a), f2b(b), f2b(c), f2b(d)};
  *(ushort4*)p = o;
}

// ---------------- weight fp32->bf16 conversion (19 arrays, one kernel) ----------------
struct CvtArgs { const float* src[19]; int len[19]; };
__global__ void k_cvt(CvtArgs a, ushort* __restrict__ dst) {
  i64 pos = ((i64)blockIdx.x * 256 + threadIdx.x) * 4;
  i64 off = 0; int s = 0;
#pragma unroll 1
  for (; s < 19; ++s) { if (pos < off + a.len[s]) break; off += a.len[s]; }
  if (s >= 19) return;
  float4 v = *(const float4*)(a.src[s] + (pos - off));
  st_bf4(dst + pos, v.x, v.y, v.z, v.w);
}

// ---------------- concat [e|c] -> X bf16 (NTOK x EMB) ----------------
__global__ void k_concat(const float* __restrict__ eq, const float* __restrict__ cq,
                         const float* __restrict__ ep, const float* __restrict__ cp,
                         ushort* __restrict__ X) {
  int idx = blockIdx.x * 256 + threadIdx.x;   // 4-elem index, grid exact
  i64 e = (i64)idx * 4;
  int row = (int)(e / EMB), c = (int)(e % EMB);
  float4 v;
  if (row < NTOKQ) {
    if (c < EDIM) v = *(const float4*)(eq + (i64)row * EDIM + c);
    else          v = *(const float4*)(cq + (i64)row * CDIM + (c - EDIM));
  } else {
    int t = row - NTOKQ;
    if (c < EDIM) v = *(const float4*)(ep + (i64)t * EDIM + c);
    else          v = *(const float4*)(cp + (i64)t * CDIM + (c - EDIM));
  }
  st_bf4(X + (i64)row * EMB + c, v.x, v.y, v.z, v.w);
}

// ---------------- MFMA bf16 GEMM: C = A(MxK) @ W(NxK)^T + b ----------------
// ACT: 0 none, 1 relu, 2 gelu, 3 sigmoid. Dual-output fp32/bf16.
template <int ACT, bool WF32, bool WBF>
__global__ __launch_bounds__(256) void k_gemm(const ushort* __restrict__ A,
                                              const ushort* __restrict__ W,
                                              const float* __restrict__ bias,
                                              float* __restrict__ Cf,
                                              ushort* __restrict__ Cb,
                                              int M, int N, int K) {
  __shared__ ushort Al[128 * 64];
  __shared__ ushort Bl[128 * 64];
  const int tid = threadIdx.x;
  const int lane = tid & 63;
  const int wave = tid >> 6;
  const int wm = wave >> 1, wn = wave & 1;
  const int r0 = blockIdx.y * 128, c0 = blockIdx.x * 128;
  const int srow = tid >> 3;      // 0..31 (+ch*32)
  const int scol = tid & 7;       // 16B slot within 128B row
  f32x4 acc[4][4] = {};
  short8 Asr[4], Bsr[4];
#pragma unroll
  for (int ch = 0; ch < 4; ++ch) {
    int row = ch * 32 + srow;
    Asr[ch] = *(const short8*)(A + (i64)(r0 + row) * K + scol * 8);
    Bsr[ch] = *(const short8*)(W + (i64)(c0 + row) * K + scol * 8);
  }
  const int nk = K >> 6;
  for (int kt = 0; kt < nk; ++kt) {
#pragma unroll
    for (int ch = 0; ch < 4; ++ch) {
      int row = ch * 32 + srow;
      int slot = scol ^ (row & 7);
      *(short8*)(Al + row * 64 + slot * 8) = Asr[ch];
      *(short8*)(Bl + row * 64 + slot * 8) = Bsr[ch];
    }
    __syncthreads();
    if (kt + 1 < nk) {
      int k0 = (kt + 1) << 6;
#pragma unroll
      for (int ch = 0; ch < 4; ++ch) {
        int row = ch * 32 + srow;
        Asr[ch] = *(const short8*)(A + (i64)(r0 + row) * K + k0 + scol * 8);
        Bsr[ch] = *(const short8*)(W + (i64)(c0 + row) * K + k0 + scol * 8);
      }
    }
#pragma unroll
    for (int ks = 0; ks < 2; ++ks) {
      short8 af[4], bf[4];
      int c16 = ks * 4 + (lane >> 4);
#pragma unroll
      for (int m = 0; m < 4; ++m) {
        int arow = wm * 64 + m * 16 + (lane & 15);
        af[m] = *(const short8*)(Al + arow * 64 + ((c16 ^ (arow & 7)) * 8));
        int brow = wn * 64 + m * 16 + (lane & 15);
        bf[m] = *(const short8*)(Bl + brow * 64 + ((c16 ^ (brow & 7)) * 8));
      }
#pragma unroll
      for (int m = 0; m < 4; ++m)
#pragma unroll
        for (int n = 0; n < 4; ++n)
          acc[m][n] = __builtin_amdgcn_mfma_f32_16x16x32_bf16(af[m], bf[n], acc[m][n], 0, 0, 0);
    }
    __syncthreads();
  }
#pragma unroll
  for (int m = 0; m < 4; ++m) {
    int row = r0 + wm * 64 + m * 16 + (lane >> 4) * 4;
#pragma unroll
    for (int n = 0; n < 4; ++n) {
      int col = c0 + wn * 64 + n * 16 + (lane & 15);
      float bv = bias[col];
#pragma unroll
      for (int j = 0; j < 4; ++j) {
        if (row + j >= M) continue;
        float v = acc[m][n][j] + bv;
        if (ACT == 1) v = fmaxf(v, 0.f);
        if (ACT == 2) v = 0.5f * v * (1.f + erff(v * 0.70710678118f));
        if (ACT == 3) v = 1.f / (1.f + __expf(-v));
        if (WF32) Cf[(i64)(row + j) * N + col] = v;
        if (WBF)  Cb[(i64)(row + j) * N + col] = f2b(v);
      }
    }
  }
}

// ---------------- highway combine: h = g*t + (1-g)*x (all bf16) ----------------
__global__ void k_hwcomb(const ushort* __restrict__ T, const ushort* __restrict__ G,
                         const ushort* __restrict__ X, ushort* __restrict__ H) {
  i64 o = ((i64)blockIdx.x * 256 + threadIdx.x) * 8;
  ushort tb[8], gb[8], xb[8], hb[8];
  *(uint4*)tb = *(const uint4*)(T + o);
  *(uint4*)gb = *(const uint4*)(G + o);
  *(uint4*)xb = *(const uint4*)(X + o);
#pragma unroll
  for (int i = 0; i < 8; ++i) {
    float t = b2f(tb[i]), g = b2f(gb[i]), x = b2f(xb[i]);
    hb[i] = f2b(g * t + (1.f - g) * x);
  }
  *(uint4*)(H + o) = *(uint4*)hb;
}

// ---------------- residual + layernorm, fp32 state + bf16 copy ----------------
__global__ void k_lnres(float* __restrict__ X, ushort* __restrict__ Xb,
                        const float* __restrict__ Hh,
                        const float* __restrict__ g, const float* __restrict__ b) {
  int row = blockIdx.x;
  int lane = threadIdx.x;
  float4 xv = *(float4*)(X + (i64)row * HD + lane * 4);
  float4 hv = *(const float4*)(Hh + (i64)row * HD + lane * 4);
  float v0 = xv.x + hv.x, v1 = xv.y + hv.y, v2 = xv.z + hv.z, v3 = xv.w + hv.w;
  float m = wsum(v0 + v1 + v2 + v3) * (1.f / HD);
  float d0 = v0 - m, d1 = v1 - m, d2 = v2 - m, d3 = v3 - m;
  float var = wsum(d0 * d0 + d1 * d1 + d2 * d2 + d3 * d3) * (1.f / HD);
  float rstd = rsqrtf(var + 1e-5f);
  float4 gv = *(const float4*)(g + lane * 4);
  float4 bv = *(const float4*)(b + lane * 4);
  float4 o;
  o.x = d0 * rstd * gv.x + bv.x;
  o.y = d1 * rstd * gv.y + bv.y;
  o.z = d2 * rstd * gv.z + bv.z;
  o.w = d3 * rstd * gv.w + bv.w;
  *(float4*)(X + (i64)row * HD + lane * 4) = o;
  st_bf4(Xb + (i64)row * HD + lane * 4, o.x, o.y, o.z, o.w);
}

// ---------------- MFMA attention for PLEN sequences ----------------
// block = (seq*8+head, half). half 0: q-tiles 0..12, half 1: 13..24 (25x16=400 exact).
// K staged [400][40] bf16 (pad->16B-aligned b128, conflict-free), V transposed [32][424].
// Per wave: q-tile strip; kv pairs of 16 (K=32 mfma); online softmax via shfl_xor;
// P routed through wave-private LDS tile to form PV A-fragment.
__global__ __launch_bounds__(256) void k_attnm(const ushort* __restrict__ qkv,
                                               ushort* __restrict__ O,
                                               const int* __restrict__ lens,
                                               int tokBase) {
  __shared__ ushort Kl[400][40];    // 32000 B
  __shared__ ushort Vt[32][424];    // 27136 B
  __shared__ ushort Pl[4][16][40];  // 5120 B (per-wave)
  const int tid = threadIdx.x;
  const int lane = tid & 63;
  const int w = tid >> 6;
  const int seq = blockIdx.x >> 3, head = blockIdx.x & 7;
  const int half = blockIdx.y;
  const int len = lens[seq];
  const i64 base = tokBase + (i64)seq * PLEN;
  const ushort* Qp = qkv + base * 768 + head * 32;
  const ushort* Kp = Qp + 256;
  const ushort* Vp = Qp + 512;
  // stage K row-major, V transposed
  for (int idx = tid; idx < 1600; idx += 256) {
    int t = idx >> 2, c = (idx & 3) << 3;
    *(uint4*)&Kl[t][c] = *(const uint4*)(Kp + (i64)t * 768 + c);
    ushort vv[8];
    *(uint4*)vv = *(const uint4*)(Vp + (i64)t * 768 + c);
#pragma unroll
    for (int j = 0; j < 8; ++j) Vt[c + j][t] = vv[j];
  }
  // zero V padding cols 400..415 (avoid NaN garbage into PV mfma)
  for (int idx = tid; idx < 512; idx += 256) Vt[idx & 31][400 + (idx >> 5)] = 0;
  __syncthreads();
  const int h = lane >> 4, lo = lane & 15;
  const int NT = half ? 12 : 13;
  const int tbase = half * 13;
  const int npair = (len + 31) >> 5;
  for (int t = w; t < NT; t += 4) {
    int qt = tbase + t;
    short8 qf = *(const short8*)(Qp + (i64)(qt * 16 + lo) * 768 + h * 8);
    f32x4 o0 = {}, o1 = {};
    float m[4] = {-1e30f, -1e30f, -1e30f, -1e30f};
    float l[4] = {0.f, 0.f, 0.f, 0.f};
    for (int kp = 0; kp < npair; ++kp) {
      int kv0 = kp << 5;
      short8 kb0 = *(const short8*)&Kl[kv0 + lo][h * 8];
      short8 kb1 = *(const short8*)&Kl[kv0 + 16 + lo][h * 8];
      f32x4 z = {};
      f32x4 s0 = __builtin_amdgcn_mfma_f32_16x16x32_bf16(qf, kb0, z, 0, 0, 0);
      f32x4 s1 = __builtin_amdgcn_mfma_f32_16x16x32_bf16(qf, kb1, z, 0, 0, 0);
      bool tail = (kv0 + 32 > len);
      bool ma = tail && (kv0 + lo >= len);
      bool mb = tail && (kv0 + 16 + lo >= len);
#pragma unroll
      for (int r = 0; r < 4; ++r) {
        s0[r] = ma ? -1e30f : s0[r] * ATT_SCALE;
        s1[r] = mb ? -1e30f : s1[r] * ATT_SCALE;
      }
      float tm[4], p0[4], p1[4], ts[4];
#pragma unroll
      for (int r = 0; r < 4; ++r) tm[r] = fmaxf(s0[r], s1[r]);
#pragma unroll
      for (int msk = 1; msk < 16; msk <<= 1)
#pragma unroll
        for (int r = 0; r < 4; ++r) tm[r] = fmaxf(tm[r], __shfl_xor(tm[r], msk));
#pragma unroll
      for (int r = 0; r < 4; ++r) {
        float mn = fmaxf(m[r], tm[r]);
        float corr = __expf(m[r] - mn);
        m[r] = mn;
        p0[r] = __expf(s0[r] - mn);
        p1[r] = __expf(s1[r] - mn);
        ts[r] = p0[r] + p1[r];
        l[r] *= corr;
        o0[r] *= corr;
        o1[r] *= corr;
      }
#pragma unroll
      for (int msk = 1; msk < 16; msk <<= 1)
#pragma unroll
        for (int r = 0; r < 4; ++r) ts[r] += __shfl_xor(ts[r], msk);
#pragma unroll
      for (int r = 0; r < 4; ++r) l[r] += ts[r];
      // P -> wave-private LDS tile (bf16), then read back as PV A-fragment
#pragma unroll
      for (int r = 0; r < 4; ++r) {
        Pl[w][4 * h + r][lo] = f2b(p0[r]);
        Pl[w][4 * h + r][16 + lo] = f2b(p1[r]);
      }
      short8 pa = *(const short8*)&Pl[w][lo][h * 8];
      short8 vb0 = *(const short8*)&Vt[lo][kv0 + h * 8];
      short8 vb1 = *(const short8*)&Vt[16 + lo][kv0 + h * 8];
      o0 = __builtin_amdgcn_mfma_f32_16x16x32_bf16(pa, vb0, o0, 0, 0, 0);
      o1 = __builtin_amdgcn_mfma_f32_16x16x32_bf16(pa, vb1, o1, 0, 0, 0);
    }
#pragma unroll
    for (int r = 0; r < 4; ++r) {
      float inv = 1.f / l[r];
      i64 row = base + qt * 16 + 4 * h + r;
      O[row * 256 + head * 32 + lo] = f2b(o0[r] * inv);
      O[row * 256 + head * 32 + 16 + lo] = f2b(o1[r] * inv);
    }
  }
}

// ---------------- small vector attention for QLEN sequences (bf16 in/out) ----------------
__global__ __launch_bounds__(64) void k_attnq(const ushort* __restrict__ qkv,
                                              ushort* __restrict__ O,
                                              const int* __restrict__ lens,
                                              int tokBase) {
  __shared__ float Ks[QLEN * DH];
  __shared__ float Vs[QLEN * DH];
  int seq = blockIdx.x >> 3, head = blockIdx.x & 7;
  int len = lens[seq];
  i64 base = tokBase + (i64)seq * QLEN;
  const ushort* Qp = qkv + base * 768 + head * 32;
  for (int idx = threadIdx.x; idx < QLEN * 4; idx += 64) {
    int t = idx >> 2, c = (idx & 3) * 8;
    ushort tmp[8];
    *(uint4*)tmp = *(const uint4*)(Qp + 256 + (i64)t * 768 + c);
#pragma unroll
    for (int j = 0; j < 8; ++j) Ks[t * DH + c + j] = b2f(tmp[j]);
    *(uint4*)tmp = *(const uint4*)(Qp + 512 + (i64)t * 768 + c);
#pragma unroll
    for (int j = 0; j < 8; ++j) Vs[t * DH + c + j] = b2f(tmp[j]);
  }
  __syncthreads();
  int r = threadIdx.x;
  if (r >= QLEN) return;
  float q[DH];
#pragma unroll
  for (int c = 0; c < 4; ++c) {
    ushort qb[8];
    *(uint4*)qb = *(const uint4*)(Qp + (i64)r * 768 + c * 8);
#pragma unroll
    for (int j = 0; j < 8; ++j) q[c * 8 + j] = b2f(qb[j]);
  }
  float mx = -1e30f, l = 0.f, acc[DH] = {};
  for (int j = 0; j < len; ++j) {
    float s = 0.f;
#pragma unroll
    for (int d = 0; d < DH; ++d) s += q[d] * Ks[j * DH + d];
    s *= ATT_SCALE;
    float mn = fmaxf(mx, s);
    float corr = __expf(mx - mn);
    float e = __expf(s - mn);
    l = l * corr + e;
#pragma unroll
    for (int d = 0; d < DH; ++d) acc[d] = acc[d] * corr + e * Vs[j * DH + d];
    mx = mn;
  }
  float inv = 1.f / l;
  ushort* op = O + (base + r) * 256 + head * 32;
#pragma unroll
  for (int d = 0; d < DH; ++d) op[d] = f2b(acc[d] * inv);
}

// ---------------- row dot with weight vector (len HD) ----------------
__global__ void k_rowdot(const float* __restrict__ X, const float* __restrict__ w,
                         float* __restrict__ out) {
  int row = blockIdx.x;
  int lane = threadIdx.x;
  float4 x = *(const float4*)(X + (i64)row * HD + lane * 4);
  float4 wv = *(const float4*)(w + lane * 4);
  float s = wsum(x.x * wv.x + x.y * wv.y + x.z * wv.z + x.w * wv.w);
  if (lane == 0) out[row] = s;
}

// ---------------- U tile: block = (bk, ptile of 16) ----------------
__global__ __launch_bounds__(256) void k_u2(const float* __restrict__ E,
                                            const float* __restrict__ dual,
                                            const float* __restrict__ epwp,
                                            const float* __restrict__ eqwq,
                                            float* __restrict__ U) {
  __shared__ float Eqx[QLEN][260];   // 52 KB, 16B-aligned rows
  int bk = blockIdx.x, pt = blockIdx.y, b = bk / NPAS;
  for (int idx = threadIdx.x; idx < QLEN * 64; idx += 256) {
    int q = idx >> 6, h4 = idx & 63;
    float4 ev = *(const float4*)(E + (i64)(b * QLEN + q) * HD + h4 * 4);
    float4 dv = *(const float4*)(dual + 2 * HD + h4 * 4);
    *(float4*)(&Eqx[q][h4 * 4]) = make_float4(ev.x * dv.x, ev.y * dv.y, ev.z * dv.z, ev.w * dv.w);
  }
  __syncthreads();
  int pi = threadIdx.x >> 4, qi = threadIdx.x & 15;
  int p = pt * 16 + pi;
  const float* ep = E + (i64)(NTOKQ + bk * PLEN + p) * HD;
  float acc[4] = {};
#pragma unroll 4
  for (int h4 = 0; h4 < 64; ++h4) {
    float4 e4 = *(const float4*)(ep + h4 * 4);
#pragma unroll
    for (int m = 0; m < 4; ++m) {
      int q = qi + m * 16;
      int qq = q < QLEN ? q : QLEN - 1;
      float4 x4 = *(const float4*)(&Eqx[qq][h4 * 4]);
      acc[m] += e4.x * x4.x + e4.y * x4.y + e4.z * x4.z + e4.w * x4.w;
    }
  }
  float pw = epwp[bk * PLEN + p];
#pragma unroll
  for (int m = 0; m < 4; ++m) {
    int q = qi + m * 16;
    if (q < QLEN)
      U[(i64)(bk * PLEN + p) * QLEN + q] = pw + eqwq[b * QLEN + q] + acc[m];
  }
}

// ---------------- Bsm: softmax over p (column) ----------------
__global__ void k_softmax_col(const float* __restrict__ U, float* __restrict__ Bsm) {
  int col = blockIdx.x * 4 + (threadIdx.x >> 6);  // 2000 columns
  int lane = threadIdx.x & 63;
  int bk = col / QLEN, q = col % QLEN;
  const float* Ucol = U + (i64)bk * PLEN * QLEN + q;
  float v[7];
#pragma unroll
  for (int i = 0; i < 7; ++i) {
    int p = lane + i * 64;
    v[i] = (p < PLEN) ? Ucol[(i64)p * QLEN] : -1e30f;
  }
  float m = v[0];
#pragma unroll
  for (int i = 1; i < 7; ++i) m = fmaxf(m, v[i]);
  m = wmax(m);
  float s = 0.f;
#pragma unroll
  for (int i = 0; i < 7; ++i) {
    int p = lane + i * 64;
    v[i] = (p < PLEN) ? __expf(v[i] - m) : 0.f;
    s += v[i];
  }
  s = wsum(s);
  float inv = 1.f / s;
#pragma unroll
  for (int i = 0; i < 7; ++i) {
    int p = lane + i * 64;
    if (p < PLEN) Bsm[(i64)bk * PLEN * QLEN + (i64)p * QLEN + q] = v[i] * inv;
  }
}

// ---------------- Asm: row softmax in place ----------------
__global__ void k_softmax_row(float* __restrict__ U) {
  int row = blockIdx.x * 4 + (threadIdx.x >> 6);
  int lane = threadIdx.x & 63;
  float v = (lane < QLEN) ? U[(i64)row * QLEN + lane] : -1e30f;
  float m = wmax(v);
  float e = (lane < QLEN) ? __expf(v - m) : 0.f;
  float s = wsum(e);
  if (lane < QLEN) U[(i64)row * QLEN + lane] = e / s;
}

// ---------------- A-type: block = (bk, ptile of 16); thread = h ----------------
__global__ __launch_bounds__(256) void k_aX2(const float* __restrict__ inQ, int strideSel,
                                             const float* __restrict__ Asm,
                                             float* __restrict__ out) {
  int bk = blockIdx.x, pt = blockIdx.y, b = bk / NPAS;
  const float* in = inQ + (i64)(strideSel ? bk : b) * QLEN * HD;
  __shared__ float AsmL[16][52];
  int tid = threadIdx.x;
  for (int idx = tid; idx < 16 * QLEN; idx += 256)
    AsmL[idx / QLEN][idx % QLEN] = Asm[(i64)(bk * PLEN + pt * 16) * QLEN + idx];
  __syncthreads();
  float inr[QLEN];
#pragma unroll
  for (int q = 0; q < QLEN; ++q) inr[q] = in[(i64)q * HD + tid];
#pragma unroll 2
  for (int pl = 0; pl < 16; ++pl) {
    float a0 = 0.f, a1 = 0.f;
#pragma unroll
    for (int q = 0; q < QLEN; q += 2) { a0 += inr[q] * AsmL[pl][q]; a1 += inr[q + 1] * AsmL[pl][q + 1]; }
    out[(i64)(bk * PLEN + pt * 16 + pl) * HD + tid] = a0 + a1;
  }
}

// ---------------- B-type: block = (bk, qtile of 5); thread = h ----------------
__global__ __launch_bounds__(256) void k_bX2(const float* __restrict__ inP,
                                             const float* __restrict__ Bsm,
                                             float* __restrict__ out) {
  int bk = blockIdx.x, qt = blockIdx.y;  // q = qt*5 .. +4
  const float* in = inP + (i64)bk * PLEN * HD;
  __shared__ float BsmL[PLEN][5];
  int tid = threadIdx.x;
  for (int idx = tid; idx < PLEN * 5; idx += 256) {
    int p = idx / 5, m = idx % 5;
    BsmL[p][m] = Bsm[(i64)(bk * PLEN + p) * QLEN + qt * 5 + m];
  }
  __syncthreads();
  float acc[5] = {};
  for (int p = 0; p < PLEN; ++p) {
    float e = in[(i64)p * HD + tid];
#pragma unroll
    for (int m = 0; m < 5; ++m) acc[m] += e * BsmL[p][m];
  }
#pragma unroll
  for (int m = 0; m < 5; ++m)
    out[(i64)(bk * QLEN + qt * 5 + m) * HD + tid] = acc[m];
}

// ---------------- max over k ----------------
__global__ void k_maxk(const float* __restrict__ Bs, float* __restrict__ Bm) {
  int idx = blockIdx.x * 256 + threadIdx.x;
  if (idx >= NB * QLEN * HD) return;
  int b = idx / (QLEN * HD), r = idx % (QLEN * HD);
  float m = -1e30f;
#pragma unroll
  for (int k = 0; k < NPAS; ++k) m = fmaxf(m, Bs[(i64)(b * NPAS + k) * QLEN * HD + r]);
  Bm[idx] = m;
}

// ---------------- G build: [ep | x1 | x2 | ep*x1 | ep*x2] bf16, K=1280 ----------------
__global__ void k_gbuild(const float* __restrict__ E, const float* __restrict__ x1,
                         const float* __restrict__ x2, ushort* __restrict__ Gt, int ntok) {
  int tok = blockIdx.x * 4 + (threadIdx.x >> 6);
  int h4 = (threadIdx.x & 63) * 4;
  if (tok >= ntok) return;
  float4 ep = *(const float4*)(E + (i64)tok * HD + h4);
  float4 a1 = *(const float4*)(x1 + (i64)tok * HD + h4);
  float4 a2 = *(const float4*)(x2 + (i64)tok * HD + h4);
  ushort* g = Gt + (i64)tok * 1280;
  st_bf4(g + h4, ep.x, ep.y, ep.z, ep.w);
  st_bf4(g + 256 + h4, a1.x, a1.y, a1.z, a1.w);
  st_bf4(g + 512 + h4, a2.x, a2.y, a2.z, a2.w);
  st_bf4(g + 768 + h4, ep.x * a1.x, ep.y * a1.y, ep.z * a1.z, ep.w * a1.w);
  st_bf4(g + 1024 + h4, ep.x * a2.x, ep.y * a2.y, ep.z * a2.z, ep.w * a2.w);
}

// ---------------- outputs ----------------
__global__ void k_beta(const float* __restrict__ Mp, const float* __restrict__ rw,
                       float* __restrict__ outv) {
  int bk = blockIdx.x;
  int lane = threadIdx.x;
  const float* m1 = Mp + (i64)bk * PLEN * HD;
  float4 x = *(const float4*)(m1 + lane * 4);
  float4 w = *(const float4*)(rw + lane * 4);
  float s = wsum(x.x * w.x + x.y * w.y + x.z * w.z + x.w * w.w);
  if (lane == 0) outv[bk] = 1.f / (1.f + __expf(-s));
}

__global__ void k_prob(const float* __restrict__ Mp, const float* __restrict__ aw,
                       float* __restrict__ outv) {
  int b = blockIdx.x;
  int lane = threadIdx.x;
  float s = 0.f;
#pragma unroll
  for (int k = 0; k < NPAS; ++k) {
    const float* m1 = Mp + (i64)(b * NPAS + k) * PLEN * HD;
    float4 x = *(const float4*)(m1 + lane * 4);
    float4 w = *(const float4*)(aw + (i64)k * HD + lane * 4);
    s += x.x * w.x + x.y * w.y + x.z * w.z + x.w * w.w;
  }
  s = wsum(s);
  if (lane == 0) outv[b] = 1.f / (1.f + __expf(-s));
}

__global__ void k_masks(const int* __restrict__ qlen, const int* __restrict__ slen,
                        float* __restrict__ out) {
  int idx = blockIdx.x * 256 + threadIdx.x;
  if (idx < NTOKQ) {
    int b = idx / QLEN, i = idx % QLEN;
    out[OFF_QM + idx] = (i >= qlen[b]) ? 1.f : 0.f;
  }
  if (idx < NTOKP) {
    int s = idx / PLEN, i = idx % PLEN;
    out[OFF_PM + idx] = (i >= slen[s]) ? 1.f : 0.f;
  }
}

__global__ void k_copy4(const float* __restrict__ src, float* __restrict__ dst, int n4) {
  int idx = blockIdx.x * 256 + threadIdx.x;
  if (idx < n4) ((float4*)dst)[idx] = ((const float4*)src)[idx];
}

// =======================================================================
extern "C" void kernel_launch(void* const* d_in, const int* in_sizes, int n_in,
                              void* d_out, int out_size, void* d_ws, size_t ws_size,
                              hipStream_t stream) {
  const float* e_q = (const float*)d_in[0];
  const float* c_q = (const float*)d_in[1];
  const float* e_p = (const float*)d_in[2];
  const float* c_p = (const float*)d_in[3];
  const int* qlen = (const int*)d_in[4];
  const int* slen = (const int*)d_in[5];
  const float* hwt1w = (const float*)d_in[6];
  const float* hwt1b = (const float*)d_in[7];
  const float* hwg1w = (const float*)d_in[8];
  const float* hwg1b = (const float*)d_in[9];
  const float* hwt2w = (const float*)d_in[10];
  const float* hwt2b = (const float*)d_in[11];
  const float* hwg2w = (const float*)d_in[12];
  const float* hwg2b = (const float*)d_in[13];
  const float* slw = (const float*)d_in[14];
  const float* slb = (const float*)d_in[15];
  const float* encsW[12];
  const float* encqW[12];
  const float* encpW[12];
  for (int i = 0; i < 12; ++i) {
    encsW[i] = (const float*)d_in[16 + i];
    encqW[i] = (const float*)d_in[28 + i];
    encpW[i] = (const float*)d_in[40 + i];
  }
  const float* dualw = (const float*)d_in[52];
  const float* modqw = (const float*)d_in[53];
  const float* modqb = (const float*)d_in[54];
  const float* modpw = (const float*)d_in[55];
  const float* modpb = (const float*)d_in[56];
  const float* rankw = (const float*)d_in[57];
  const float* answ = (const float*)d_in[58];
  float* out = (float*)d_out;

  // -------- workspace layout (byte offsets) --------
  char* ws = (char*)d_ws;
  // ES region [0, 67,108,864): time-disjoint scratch
  ushort* qkvB  = (ushort*)(ws + 0);            // 16384x768 bf16 = 25,165,824
  ushort* attnO = (ushort*)(ws + 25165824);     // 16384x256 bf16 = 8,388,608 (ends 33,554,432)
  float*  t1    = (float*) (ws + 0);            // 16384x256 f32 (qkvB dead by then)
  ushort* ffB   = (ushort*)(ws + 16777216);     // 16384x1024 bf16 (ends 50,331,648)
  ushort* Tb    = (ushort*)(ws + 0);            // highway T
  ushort* Gb    = (ushort*)(ws + 33554432);     // highway G (ends 67,108,864)
  ushort* GpB   = (ushort*)(ws + 0);            // 16384x1280 bf16 = 41,943,040
  ushort* GqB   = (ushort*)(ws + 44040192);     // 256x1280 bf16
  // RA / RB
  ushort* Xbf   = (ushort*)(ws + 67108864);     // 16384x1024 bf16
  ushort* H2bf  = Xbf;
  ushort* Hbf   = (ushort*)(ws + 100663296);
  float*  A1s   = (float*) (ws + 100663296);    // 16,384,000
  float*  A2s   = (float*) (ws + 117047296);    // 16,384,000
  // persistent states
  float*  S_f32 = (float*) (ws + 134217728);
  ushort* S_bf  = (ushort*)(ws + 150994944);
  float*  Mp_f32= (float*) (ws + 159383552);
  ushort* Mp_bf = (ushort*)(ws + 176160768);
  float*  Mq_f32= (float*) (ws + 184549376);
  ushort* Mq_bf = (ushort*)(ws + 184811520);
  float*  Ubuf  = (float*) (ws + 184942592);
  float*  BsmB  = (float*) (ws + 188142592);
  float*  B1s   = (float*) (ws + 191342592);
  float*  B2s   = (float*) (ws + 193390592);
  float*  B1m   = (float*) (ws + 195438592);
  float*  B2m   = (float*) (ws + 195643392);
  float*  EPWP  = (float*) (ws + 195848192);
  float*  EQWQ  = (float*) (ws + 195912192);
  ushort* Wpool = (ushort*)(ws + 195913216);    // ends ~215.6 MB

  // -------- weight conversion --------
  CvtArgs ca;
  const float* wsrc[19] = {hwt1w, hwg1w, hwt2w, hwg2w, slw,
                           encsW[0], encsW[2], encsW[6], encsW[8],
                           encqW[0], encqW[2], encqW[6], encqW[8],
                           encpW[0], encpW[2], encpW[6], encpW[8],
                           modqw, modpw};
  const int wlen[19] = {1048576, 1048576, 1048576, 1048576, 262144,
                        393216, 131072, 524288, 524288,
                        393216, 131072, 524288, 524288,
                        393216, 131072, 524288, 524288,
                        327680, 327680};
  i64 woff[19];
  {
    i64 o = 0;
    for (int i = 0; i < 19; ++i) { ca.src[i] = wsrc[i]; ca.len[i] = wlen[i]; woff[i] = o; o += wlen[i]; }
  }
  k_cvt<<<dim3(9600), dim3(256), 0, stream>>>(ca, Wpool);
  ushort* WhT1 = Wpool + woff[0];
  ushort* WhG1 = Wpool + woff[1];
  ushort* WhT2 = Wpool + woff[2];
  ushort* WhG2 = Wpool + woff[3];
  ushort* WslB = Wpool + woff[4];
  ushort* WencB[3][4];
  for (int e = 0; e < 3; ++e)
    for (int k = 0; k < 4; ++k) WencB[e][k] = Wpool + woff[5 + e * 4 + k];
  ushort* WmodqB = Wpool + woff[17];
  ushort* WmodpB = Wpool + woff[18];

  // -------- 1. concat -> bf16 --------
  k_concat<<<dim3(NTOK * EMB / 4 / 256), dim3(256), 0, stream>>>(e_q, c_q, e_p, c_p, Xbf);

  // -------- 2. highway --------
  {
    dim3 g(8, 127);
    k_gemm<1, false, true><<<g, 256, 0, stream>>>(Xbf, WhT1, hwt1b, nullptr, Tb, NTOK, 1024, 1024);
    k_gemm<3, false, true><<<g, 256, 0, stream>>>(Xbf, WhG1, hwg1b, nullptr, Gb, NTOK, 1024, 1024);
    k_hwcomb<<<dim3(8100), dim3(256), 0, stream>>>(Tb, Gb, Xbf, Hbf);
    k_gemm<1, false, true><<<g, 256, 0, stream>>>(Hbf, WhT2, hwt2b, nullptr, Tb, NTOK, 1024, 1024);
    k_gemm<3, false, true><<<g, 256, 0, stream>>>(Hbf, WhG2, hwg2b, nullptr, Gb, NTOK, 1024, 1024);
    k_hwcomb<<<dim3(8100), dim3(256), 0, stream>>>(Tb, Gb, Hbf, H2bf);
  }

  // -------- 3. shared linear -> S --------
  k_gemm<0, true, true><<<dim3(2, 127), 256, 0, stream>>>(H2bf, WslB, slb, S_f32, S_bf, NTOK, 256, 1024);

  // -------- encoder helper --------
  struct AttnSpec { int nseq, S, base; const int* lens; };
  auto enc = [&](float* stF, ushort* stB, int M, const float* const* w, ushort* const* wb,
                 const AttnSpec* specs, int nspec) {
    int gy = (M + 127) / 128;
    for (int l = 0; l < 2; ++l) {
      k_gemm<0, false, true><<<dim3(6, gy), 256, 0, stream>>>(
          stB, wb[0] + (i64)l * 3 * HD * HD, w[1] + l * 3 * HD, nullptr, qkvB, M, 768, 256);
      for (int s = 0; s < nspec; ++s) {
        if (specs[s].S == PLEN)
          k_attnm<<<dim3(specs[s].nseq * NHEADS, 2), dim3(256), 0, stream>>>(
              qkvB, attnO, specs[s].lens, specs[s].base);
        else
          k_attnq<<<dim3(specs[s].nseq * NHEADS), dim3(64), 0, stream>>>(
              qkvB, attnO, specs[s].lens, specs[s].base);
      }
      k_gemm<0, true, false><<<dim3(2, gy), 256, 0, stream>>>(
          attnO, wb[1] + (i64)l * HD * HD, w[3] + l * HD, t1, nullptr, M, 256, 256);
      k_lnres<<<dim3(M), dim3(64), 0, stream>>>(stF, stB, t1, w[4] + l * HD, w[5] + l * HD);
      k_gemm<2, false, true><<<dim3(8, gy), 256, 0, stream>>>(
          stB, wb[2] + (i64)l * DFF * HD, w[7] + l * DFF, nullptr, ffB, M, 1024, 256);
      k_gemm<0, true, false><<<dim3(2, gy), 256, 0, stream>>>(
          ffB, wb[3] + (i64)l * HD * DFF, w[9] + l * HD, t1, nullptr, M, 256, 1024);
      k_lnres<<<dim3(M), dim3(64), 0, stream>>>(stF, stB, t1, w[10] + l * HD, w[11] + l * HD);
    }
  };

  // -------- 4. shared encoder --------
  AttnSpec specs[2] = {{NB, QLEN, 0, qlen}, {NB * NPAS, PLEN, NTOKQ, slen}};
  enc(S_f32, S_bf, NTOK, encsW, WencB[0], specs, 2);

  // -------- 5. dual attention --------
  k_rowdot<<<dim3(NTOKP), dim3(64), 0, stream>>>(S_f32 + (i64)NTOKQ * HD, dualw, EPWP);
  k_rowdot<<<dim3(NTOKQ), dim3(64), 0, stream>>>(S_f32, dualw + HD, EQWQ);
  k_u2<<<dim3(NB * NPAS, 25), dim3(256), 0, stream>>>(S_f32, dualw, EPWP, EQWQ, Ubuf);
  k_softmax_col<<<dim3(500), dim3(256), 0, stream>>>(Ubuf, BsmB);
  k_softmax_row<<<dim3(4000), dim3(256), 0, stream>>>(Ubuf);
  k_aX2<<<dim3(NB * NPAS, 25), dim3(256), 0, stream>>>(S_f32, 0, Ubuf, A1s);
  k_bX2<<<dim3(NB * NPAS, 10), dim3(256), 0, stream>>>(S_f32 + (i64)NTOKQ * HD, BsmB, B1s);
  k_aX2<<<dim3(NB * NPAS, 25), dim3(256), 0, stream>>>(B1s, 1, Ubuf, A2s);
  k_bX2<<<dim3(NB * NPAS, 10), dim3(256), 0, stream>>>(A1s, BsmB, B2s);
  k_maxk<<<dim3(200), dim3(256), 0, stream>>>(B1s, B1m);
  k_maxk<<<dim3(200), dim3(256), 0, stream>>>(B2s, B2m);

  // -------- 6. G build + mod projections --------
  k_gbuild<<<dim3(4000), dim3(256), 0, stream>>>(S_f32 + (i64)NTOKQ * HD, A1s, A2s, GpB, NTOKP);
  k_gemm<0, true, true><<<dim3(2, 125), 256, 0, stream>>>(GpB, WmodpB, modpb, Mp_f32, Mp_bf, NTOKP, 256, 1280);
  k_gbuild<<<dim3(50), dim3(256), 0, stream>>>(S_f32, B1m, B2m, GqB, NTOKQ);
  k_gemm<0, true, true><<<dim3(2, 2), 256, 0, stream>>>(GqB, WmodqB, modqb, Mq_f32, Mq_bf, NTOKQ, 256, 1280);

  // -------- 7. model encoders --------
  AttnSpec sp2 = {NB * NPAS, PLEN, 0, slen};
  enc(Mp_f32, Mp_bf, NTOKP, encpW, WencB[2], &sp2, 1);
  AttnSpec sq2 = {NB, QLEN, 0, qlen};
  enc(Mq_f32, Mq_bf, NTOKQ, encqW, WencB[1], &sq2, 1);

  // -------- 8. outputs --------
  k_beta<<<dim3(NB * NPAS), dim3(64), 0, stream>>>(Mp_f32, rankw, out + OFF_BETA);
  k_prob<<<dim3(NB), dim3(64), 0, stream>>>(Mp_f32, answ, out + OFF_PROB);
  k_copy4<<<dim3(50), dim3(256), 0, stream>>>(Mq_f32, out + OFF_MQ, NTOKQ * HD / 4);
  k_copy4<<<dim3(4000), dim3(256), 0, stream>>>(Mp_f32, out + OFF_MP, NTOKP * HD / 4);
  k_masks<<<dim3(63), dim3(256), 0, stream>>>(qlen, slen, out);
}